// Round 1
// baseline (147.299 us; speedup 1.0000x reference)
//
#include <hip/hip_runtime.h>
#include <math.h>

// Problem constants (fixed by setup_inputs): B=1, D=H=W=24, N=13824, C=128,
// NUM_HEADS=4, hc=32, KSIZE=3, K3=27.
#define NTOK 13824
#define CCH 128
#define DD3 24
#define SCALE 0.17677669529663687f  // 32^-0.5

// ---------------------------------------------------------------------------
// Fused QKV GEMM: x[N][128] @ {Wq[128][128], Wkv[128][256]} (+bias)
// grid.x = N/64 row tiles, grid.y = 3 column segments (q, kv[0:128], kv[128:256])
// 256 threads, 64x128 output tile, 4x8 register micro-tile.
// ---------------------------------------------------------------------------
__global__ __launch_bounds__(256) void qkv_gemm(
    const float* __restrict__ x,
    const float* __restrict__ Wq, const float* __restrict__ bq,
    const float* __restrict__ Wkv, const float* __restrict__ bkv,
    float* __restrict__ qb, float* __restrict__ kvb)
{
    const int row0 = blockIdx.x * 64;
    const int seg  = blockIdx.y;
    const int t    = threadIdx.x;

    __shared__ float xs[128][68];   // x tile, transposed: xs[k][m]
    __shared__ float wsh[64][128];  // weight chunk: wsh[k][n]

    // load x tile (64 rows x 128 cols), transposed into LDS
    #pragma unroll
    for (int i = 0; i < 32; ++i) {
        int e = t + i * 256;
        int r = e >> 7, c = e & 127;
        xs[c][r] = x[(row0 + r) * CCH + c];
    }

    const float* Wsrc;
    const float* bsrc;
    int ldw, coff;
    if (seg == 0) { Wsrc = Wq;  bsrc = bq;  ldw = 128; coff = 0; }
    else          { Wsrc = Wkv; bsrc = bkv; ldw = 256; coff = (seg - 1) * 128; }

    float acc[4][8];
    #pragma unroll
    for (int r = 0; r < 4; ++r)
        #pragma unroll
        for (int c = 0; c < 8; ++c) acc[r][c] = 0.f;

    const int tx = t & 15;   // column group (8 cols each)
    const int ty = t >> 4;   // row group (4 rows each)

    for (int kc = 0; kc < 2; ++kc) {
        __syncthreads();
        #pragma unroll
        for (int i = 0; i < 32; ++i) {
            int e = t + i * 256;
            int kr = e >> 7, c = e & 127;
            wsh[kr][c] = Wsrc[(kc * 64 + kr) * ldw + coff + c];
        }
        __syncthreads();
        #pragma unroll
        for (int k = 0; k < 64; ++k) {
            float a[4], b[8];
            #pragma unroll
            for (int r = 0; r < 4; ++r) a[r] = xs[kc * 64 + k][ty * 4 + r];
            #pragma unroll
            for (int c = 0; c < 8; ++c) b[c] = wsh[k][tx * 8 + c];
            #pragma unroll
            for (int r = 0; r < 4; ++r)
                #pragma unroll
                for (int c = 0; c < 8; ++c)
                    acc[r][c] += a[r] * b[c];
        }
    }

    #pragma unroll
    for (int r = 0; r < 4; ++r) {
        int row = row0 + ty * 4 + r;
        #pragma unroll
        for (int c = 0; c < 8; ++c) {
            int col = tx * 8 + c;
            float v = acc[r][c] + bsrc[coff + col];
            if (seg == 0) qb[row * CCH + col] = v * SCALE;
            else          kvb[row * 256 + coff + col] = v;
        }
    }
}

// ---------------------------------------------------------------------------
// 27-neighbor attention. 128 threads per voxel (2 voxels per 256-thread block).
// Thread c in [0,128): head = c>>5, in-head channel = c&31.
// OOB neighbors: logit = 0 (reference pads kv with zeros), v = 0.
// ---------------------------------------------------------------------------
__global__ __launch_bounds__(256) void attn3d(
    const float* __restrict__ qb, const float* __restrict__ kvb,
    float* __restrict__ ao)
{
    const int t = threadIdx.x;
    const int n = blockIdx.x * 2 + (t >> 7);
    const int c = t & 127;

    const int w = n % DD3;
    const int h = (n / DD3) % DD3;
    const int d = n / (DD3 * DD3);

    const float qv = qb[n * CCH + c];

    float logit[27];
    #pragma unroll
    for (int idx = 0; idx < 27; ++idx) {
        const int i = idx / 9, j = (idx / 3) % 3, l = idx % 3;
        const int dd = d + i - 1, hh = h + j - 1, ww = w + l - 1;
        const bool ok = (unsigned)dd < DD3 && (unsigned)hh < DD3 && (unsigned)ww < DD3;
        float p = 0.f;
        if (ok) {
            const int n2 = (dd * DD3 + hh) * DD3 + ww;
            p = qv * kvb[n2 * 256 + c];
        }
        // sum over the 32 channels of this head (lanes share head group)
        #pragma unroll
        for (int m = 16; m >= 1; m >>= 1)
            p += __shfl_xor(p, m, 64);
        logit[idx] = p;   // exactly 0 for OOB (all lanes contributed 0)
    }

    float mx = logit[0];
    #pragma unroll
    for (int idx = 1; idx < 27; ++idx) mx = fmaxf(mx, logit[idx]);
    float s = 0.f;
    #pragma unroll
    for (int idx = 0; idx < 27; ++idx) {
        logit[idx] = __expf(logit[idx] - mx);
        s += logit[idx];
    }
    const float inv = 1.f / s;

    float out = 0.f;
    #pragma unroll
    for (int idx = 0; idx < 27; ++idx) {
        const int i = idx / 9, j = (idx / 3) % 3, l = idx % 3;
        const int dd = d + i - 1, hh = h + j - 1, ww = w + l - 1;
        if ((unsigned)dd < DD3 && (unsigned)hh < DD3 && (unsigned)ww < DD3) {
            const int n2 = (dd * DD3 + hh) * DD3 + ww;
            out += logit[idx] * kvb[n2 * 256 + 128 + c];
        }
    }
    ao[n * CCH + c] = out * inv;
}

// ---------------------------------------------------------------------------
// Output projection: ao[N][128] @ Wp[128][128] + bp -> out
// ---------------------------------------------------------------------------
__global__ __launch_bounds__(256) void proj_gemm(
    const float* __restrict__ ao,
    const float* __restrict__ Wp, const float* __restrict__ bp,
    float* __restrict__ out)
{
    const int row0 = blockIdx.x * 64;
    const int t    = threadIdx.x;

    __shared__ float xs[128][68];
    __shared__ float wsh[64][128];

    #pragma unroll
    for (int i = 0; i < 32; ++i) {
        int e = t + i * 256;
        int r = e >> 7, c = e & 127;
        xs[c][r] = ao[(row0 + r) * CCH + c];
    }

    float acc[4][8];
    #pragma unroll
    for (int r = 0; r < 4; ++r)
        #pragma unroll
        for (int c = 0; c < 8; ++c) acc[r][c] = 0.f;

    const int tx = t & 15;
    const int ty = t >> 4;

    for (int kc = 0; kc < 2; ++kc) {
        __syncthreads();
        #pragma unroll
        for (int i = 0; i < 32; ++i) {
            int e = t + i * 256;
            int kr = e >> 7, c = e & 127;
            wsh[kr][c] = Wp[(kc * 64 + kr) * CCH + c];
        }
        __syncthreads();
        #pragma unroll
        for (int k = 0; k < 64; ++k) {
            float a[4], b[8];
            #pragma unroll
            for (int r = 0; r < 4; ++r) a[r] = xs[kc * 64 + k][ty * 4 + r];
            #pragma unroll
            for (int c = 0; c < 8; ++c) b[c] = wsh[k][tx * 8 + c];
            #pragma unroll
            for (int r = 0; r < 4; ++r)
                #pragma unroll
                for (int c = 0; c < 8; ++c)
                    acc[r][c] += a[r] * b[c];
        }
    }

    #pragma unroll
    for (int r = 0; r < 4; ++r) {
        int row = row0 + ty * 4 + r;
        #pragma unroll
        for (int c = 0; c < 8; ++c) {
            int col = tx * 8 + c;
            out[row * CCH + col] = acc[r][c] + bp[col];
        }
    }
}

extern "C" void kernel_launch(void* const* d_in, const int* in_sizes, int n_in,
                              void* d_out, int out_size, void* d_ws, size_t ws_size,
                              hipStream_t stream) {
    const float* x   = (const float*)d_in[0];
    const float* Wq  = (const float*)d_in[1];
    const float* bq  = (const float*)d_in[2];
    const float* Wkv = (const float*)d_in[3];
    const float* bkv = (const float*)d_in[4];
    const float* Wp  = (const float*)d_in[5];
    const float* bp  = (const float*)d_in[6];
    float* out = (float*)d_out;

    float* qb  = (float*)d_ws;                    // N*128 floats
    float* kvb = qb + (size_t)NTOK * CCH;         // N*256 floats
    float* ao  = kvb + (size_t)NTOK * 256;        // N*128 floats

    dim3 g1(NTOK / 64, 3);
    qkv_gemm<<<g1, 256, 0, stream>>>(x, Wq, bq, Wkv, bkv, qb, kvb);
    attn3d<<<NTOK / 2, 256, 0, stream>>>(qb, kvb, ao);
    proj_gemm<<<NTOK / 64, 256, 0, stream>>>(ao, Wp, bp, out);
}

// Round 3
// 98.163 us; speedup vs baseline: 1.5006x; 1.5006x over previous
//
#include <hip/hip_runtime.h>
#include <math.h>

// Problem constants (fixed by setup_inputs): B=1, D=H=W=24, N=13824, C=128,
// NUM_HEADS=4, hc=32, KSIZE=3, K3=27.
#define NTOK 13824
#define CCH 128
#define DD3 24
#define SCALE 0.17677669529663687f  // 32^-0.5

// ---------------------------------------------------------------------------
// Fused QKV GEMM: x[N][128] @ {Wq[128][128], Wkv[128][256]} (+bias)
// grid.x = N/64 row tiles, grid.y = 3 column segments (q, kv[0:128], kv[128:256])
// 256 threads, 64x128 output tile, 4x8 register micro-tile.
// ---------------------------------------------------------------------------
__global__ __launch_bounds__(256) void qkv_gemm(
    const float* __restrict__ x,
    const float* __restrict__ Wq, const float* __restrict__ bq,
    const float* __restrict__ Wkv, const float* __restrict__ bkv,
    float* __restrict__ qb, float* __restrict__ kvb)
{
    const int row0 = blockIdx.x * 64;
    const int seg  = blockIdx.y;
    const int t    = threadIdx.x;

    __shared__ float xs[128][68];   // x tile, transposed: xs[k][m]
    __shared__ float wsh[64][128];  // weight chunk: wsh[k][n]

    // load x tile (64 rows x 128 cols), transposed into LDS
    #pragma unroll
    for (int i = 0; i < 32; ++i) {
        int e = t + i * 256;
        int r = e >> 7, c = e & 127;
        xs[c][r] = x[(row0 + r) * CCH + c];
    }

    const float* Wsrc;
    const float* bsrc;
    int ldw, coff;
    if (seg == 0) { Wsrc = Wq;  bsrc = bq;  ldw = 128; coff = 0; }
    else          { Wsrc = Wkv; bsrc = bkv; ldw = 256; coff = (seg - 1) * 128; }

    float acc[4][8];
    #pragma unroll
    for (int r = 0; r < 4; ++r)
        #pragma unroll
        for (int c = 0; c < 8; ++c) acc[r][c] = 0.f;

    const int tx = t & 15;   // column group (8 cols each)
    const int ty = t >> 4;   // row group (4 rows each)

    for (int kc = 0; kc < 2; ++kc) {
        __syncthreads();
        #pragma unroll
        for (int i = 0; i < 32; ++i) {
            int e = t + i * 256;
            int kr = e >> 7, c = e & 127;
            wsh[kr][c] = Wsrc[(kc * 64 + kr) * ldw + coff + c];
        }
        __syncthreads();
        #pragma unroll
        for (int k = 0; k < 64; ++k) {
            float a[4], b[8];
            #pragma unroll
            for (int r = 0; r < 4; ++r) a[r] = xs[kc * 64 + k][ty * 4 + r];
            #pragma unroll
            for (int c = 0; c < 8; ++c) b[c] = wsh[k][tx * 8 + c];
            #pragma unroll
            for (int r = 0; r < 4; ++r)
                #pragma unroll
                for (int c = 0; c < 8; ++c)
                    acc[r][c] += a[r] * b[c];
        }
    }

    #pragma unroll
    for (int r = 0; r < 4; ++r) {
        int row = row0 + ty * 4 + r;
        #pragma unroll
        for (int c = 0; c < 8; ++c) {
            int col = tx * 8 + c;
            float v = acc[r][c] + bsrc[coff + col];
            if (seg == 0) qb[row * CCH + col] = v * SCALE;
            else          kvb[row * 256 + coff + col] = v;
        }
    }
}

// ---------------------------------------------------------------------------
// 27-neighbor attention, float4 version.
// 32 threads per voxel (8 voxels per 256-thread block).
// Thread sub = t&31 owns channels [sub*4, sub*4+4) as a float4.
// Head = sub>>3; the 8 lanes of a head reduce via __shfl_xor 1,2,4.
// OOB neighbors: logit = 0 (reference pads kv with zeros), v = 0.
// ---------------------------------------------------------------------------
__global__ __launch_bounds__(256) void attn3d(
    const float4* __restrict__ qb4, const float4* __restrict__ kvb4,
    float4* __restrict__ ao4)
{
    const int t   = threadIdx.x;
    const int n   = blockIdx.x * 8 + (t >> 5);
    const int sub = t & 31;

    const int w = n % DD3;
    const int h = (n / DD3) % DD3;
    const int d = n / (DD3 * DD3);

    const float4 q = qb4[n * 32 + sub];

    int   nb[27];     // neighbor base index into kvb4 (float4 units), -1 if OOB
    float logit[27];

    #pragma unroll
    for (int idx = 0; idx < 27; ++idx) {
        const int i = idx / 9, j = (idx / 3) % 3, l = idx % 3;
        const int dd = d + i - 1, hh = h + j - 1, ww = w + l - 1;
        const bool ok = (unsigned)dd < DD3 && (unsigned)hh < DD3 && (unsigned)ww < DD3;
        nb[idx] = ok ? ((dd * DD3 + hh) * DD3 + ww) * 64 : -1;
    }

    #pragma unroll
    for (int idx = 0; idx < 27; ++idx) {
        float p = 0.f;
        if (nb[idx] >= 0) {
            const float4 kk = kvb4[nb[idx] + sub];
            p = q.x * kk.x + q.y * kk.y + q.z * kk.z + q.w * kk.w;
        }
        p += __shfl_xor(p, 1);
        p += __shfl_xor(p, 2);
        p += __shfl_xor(p, 4);
        logit[idx] = p;   // exactly 0 for OOB
    }

    float mx = logit[0];
    #pragma unroll
    for (int idx = 1; idx < 27; ++idx) mx = fmaxf(mx, logit[idx]);
    float s = 0.f;
    #pragma unroll
    for (int idx = 0; idx < 27; ++idx) {
        logit[idx] = __expf(logit[idx] - mx);
        s += logit[idx];
    }
    const float inv = 1.f / s;

    float4 acc = {0.f, 0.f, 0.f, 0.f};
    #pragma unroll
    for (int idx = 0; idx < 27; ++idx) {
        if (nb[idx] >= 0) {
            const float4 vv = kvb4[nb[idx] + 32 + sub];
            acc.x += logit[idx] * vv.x;
            acc.y += logit[idx] * vv.y;
            acc.z += logit[idx] * vv.z;
            acc.w += logit[idx] * vv.w;
        }
    }
    acc.x *= inv; acc.y *= inv; acc.z *= inv; acc.w *= inv;
    ao4[n * 32 + sub] = acc;
}

// ---------------------------------------------------------------------------
// Output projection: ao[N][128] @ Wp[128][128] + bp -> out
// ---------------------------------------------------------------------------
__global__ __launch_bounds__(256) void proj_gemm(
    const float* __restrict__ ao,
    const float* __restrict__ Wp, const float* __restrict__ bp,
    float* __restrict__ out)
{
    const int row0 = blockIdx.x * 64;
    const int t    = threadIdx.x;

    __shared__ float xs[128][68];
    __shared__ float wsh[64][128];

    #pragma unroll
    for (int i = 0; i < 32; ++i) {
        int e = t + i * 256;
        int r = e >> 7, c = e & 127;
        xs[c][r] = ao[(row0 + r) * CCH + c];
    }

    float acc[4][8];
    #pragma unroll
    for (int r = 0; r < 4; ++r)
        #pragma unroll
        for (int c = 0; c < 8; ++c) acc[r][c] = 0.f;

    const int tx = t & 15;
    const int ty = t >> 4;

    for (int kc = 0; kc < 2; ++kc) {
        __syncthreads();
        #pragma unroll
        for (int i = 0; i < 32; ++i) {
            int e = t + i * 256;
            int kr = e >> 7, c = e & 127;
            wsh[kr][c] = Wp[(kc * 64 + kr) * CCH + c];
        }
        __syncthreads();
        #pragma unroll
        for (int k = 0; k < 64; ++k) {
            float a[4], b[8];
            #pragma unroll
            for (int r = 0; r < 4; ++r) a[r] = xs[kc * 64 + k][ty * 4 + r];
            #pragma unroll
            for (int c = 0; c < 8; ++c) b[c] = wsh[k][tx * 8 + c];
            #pragma unroll
            for (int r = 0; r < 4; ++r)
                #pragma unroll
                for (int c = 0; c < 8; ++c)
                    acc[r][c] += a[r] * b[c];
        }
    }

    #pragma unroll
    for (int r = 0; r < 4; ++r) {
        int row = row0 + ty * 4 + r;
        #pragma unroll
        for (int c = 0; c < 8; ++c) {
            int col = tx * 8 + c;
            out[row * CCH + col] = acc[r][c] + bp[col];
        }
    }
}

extern "C" void kernel_launch(void* const* d_in, const int* in_sizes, int n_in,
                              void* d_out, int out_size, void* d_ws, size_t ws_size,
                              hipStream_t stream) {
    const float* x   = (const float*)d_in[0];
    const float* Wq  = (const float*)d_in[1];
    const float* bq  = (const float*)d_in[2];
    const float* Wkv = (const float*)d_in[3];
    const float* bkv = (const float*)d_in[4];
    const float* Wp  = (const float*)d_in[5];
    const float* bp  = (const float*)d_in[6];
    float* out = (float*)d_out;

    float* qb  = (float*)d_ws;                    // N*128 floats
    float* kvb = qb + (size_t)NTOK * CCH;         // N*256 floats
    float* ao  = kvb + (size_t)NTOK * 256;        // N*128 floats

    dim3 g1(NTOK / 64, 3);
    qkv_gemm<<<g1, 256, 0, stream>>>(x, Wq, bq, Wkv, bkv, qb, kvb);
    attn3d<<<NTOK / 2 / 4, 256, 0, stream>>>((const float4*)qb, (const float4*)kvb,
                                             (float4*)ao);
    proj_gemm<<<NTOK / 64, 256, 0, stream>>>(ao, Wp, bp, out);
}

// Round 4
// 91.963 us; speedup vs baseline: 1.6017x; 1.0674x over previous
//
#include <hip/hip_runtime.h>
#include <math.h>

// Problem constants: B=1, D=H=W=24, N=13824, C=128, NUM_HEADS=4, hc=32, K3=27.
#define NTOK 13824
#define CCH 128
#define DD3 24
#define SCALE 0.17677669529663687f  // 32^-0.5

typedef float  f32x4  __attribute__((ext_vector_type(4)));
typedef short  s16x8  __attribute__((ext_vector_type(8)));

__device__ __forceinline__ ushort bf16_rtn(float f) {
    unsigned u = __float_as_uint(f);
    unsigned r = u + 0x7fffu + ((u >> 16) & 1u);
    return (ushort)(r >> 16);
}
__device__ __forceinline__ float bf16_f32(ushort h) {
    return __uint_as_float(((unsigned)h) << 16);
}

// ---------------------------------------------------------------------------
// prep_x: x f32 [N][128] -> x_hi, x_lo bf16 (split: x = hi + lo, ~f32 exact)
// one thread per 4 elements.
// ---------------------------------------------------------------------------
__global__ __launch_bounds__(256) void prep_x(
    const float4* __restrict__ x4, ushort4* __restrict__ xh, ushort4* __restrict__ xl)
{
    const int i = blockIdx.x * 256 + threadIdx.x;   // < N*128/4
    float4 v = x4[i];
    ushort4 h, lo;
    h.x = bf16_rtn(v.x); lo.x = bf16_rtn(v.x - bf16_f32(h.x));
    h.y = bf16_rtn(v.y); lo.y = bf16_rtn(v.y - bf16_f32(h.y));
    h.z = bf16_rtn(v.z); lo.z = bf16_rtn(v.z - bf16_f32(h.z));
    h.w = bf16_rtn(v.w); lo.w = bf16_rtn(v.w - bf16_f32(h.w));
    xh[i] = h; xl[i] = lo;
}

// ---------------------------------------------------------------------------
// prep_w: transpose + split all three weight mats into wt[512][128] bf16 hi/lo.
// rows 0-127: Wq cols; 128-383: Wkv cols; 384-511: Wp cols.  wt[n][k] = W[k][n].
// ---------------------------------------------------------------------------
__global__ __launch_bounds__(256) void prep_w(
    const float* __restrict__ Wq, const float* __restrict__ Wkv,
    const float* __restrict__ Wp,
    ushort* __restrict__ wth, ushort* __restrict__ wtl)
{
    const int i  = blockIdx.x * 256 + threadIdx.x;  // 0..16383
    const int rr = i >> 5;                          // 0..511
    const int k4 = (i & 31) * 4;
    const float* W; int col, ldw;
    if (rr < 128)      { W = Wq;  col = rr;       ldw = 128; }
    else if (rr < 384) { W = Wkv; col = rr - 128; ldw = 256; }
    else               { W = Wp;  col = rr - 384; ldw = 128; }
    #pragma unroll
    for (int j = 0; j < 4; ++j) {
        float v = W[(k4 + j) * ldw + col];
        ushort h = bf16_rtn(v);
        wth[rr * 128 + k4 + j] = h;
        wtl[rr * 128 + k4 + j] = bf16_rtn(v - bf16_f32(h));
    }
}

// ---------------------------------------------------------------------------
// Split-bf16 MFMA GEMM for QKV: [N][128] x wt-rows[0:384] -> qb (scaled) | kvb
// block = 256 thr (4 waves); block tile 64 rows x 64 cols; wave = 16 rows.
// grid = (216, 6).  No LDS.
// ---------------------------------------------------------------------------
__global__ __launch_bounds__(256) void qkv_mfma(
    const ushort* __restrict__ xh, const ushort* __restrict__ xl,
    const ushort* __restrict__ wth, const ushort* __restrict__ wtl,
    const float* __restrict__ bq, const float* __restrict__ bkv,
    float* __restrict__ qb, float* __restrict__ kvb)
{
    const int t  = threadIdx.x;
    const int wv = t >> 6, l = t & 63;
    const int lm = l & 15, lk = l >> 4;
    const int row = blockIdx.x * 64 + wv * 16 + lm;   // A row for this lane
    const int n0  = blockIdx.y * 64;                  // output col base
    const int ko  = lk * 8;

    f32x4 acc[4];
    #pragma unroll
    for (int nt = 0; nt < 4; ++nt)
        #pragma unroll
        for (int r = 0; r < 4; ++r) acc[nt][r] = 0.f;

    #pragma unroll
    for (int kb = 0; kb < 4; ++kb) {
        const int k0 = kb * 32;
        const s16x8 ah = *(const s16x8*)(xh + row * 128 + k0 + ko);
        const s16x8 al = *(const s16x8*)(xl + row * 128 + k0 + ko);
        #pragma unroll
        for (int nt = 0; nt < 4; ++nt) {
            const int wr = n0 + nt * 16 + lm;
            const s16x8 bh = *(const s16x8*)(wth + wr * 128 + k0 + ko);
            const s16x8 bl = *(const s16x8*)(wtl + wr * 128 + k0 + ko);
            acc[nt] = __builtin_amdgcn_mfma_f32_16x16x32_bf16(ah, bh, acc[nt], 0, 0, 0);
            acc[nt] = __builtin_amdgcn_mfma_f32_16x16x32_bf16(ah, bl, acc[nt], 0, 0, 0);
            acc[nt] = __builtin_amdgcn_mfma_f32_16x16x32_bf16(al, bh, acc[nt], 0, 0, 0);
        }
    }

    const int orow0 = blockIdx.x * 64 + wv * 16 + lk * 4;
    #pragma unroll
    for (int nt = 0; nt < 4; ++nt) {
        const int col = n0 + nt * 16 + lm;
        if (col < 128) {
            const float b = bq[col];
            #pragma unroll
            for (int r = 0; r < 4; ++r)
                qb[(orow0 + r) * 128 + col] = (acc[nt][r] + b) * SCALE;
        } else {
            const int c2 = col - 128;
            const float b = bkv[c2];
            #pragma unroll
            for (int r = 0; r < 4; ++r)
                kvb[(orow0 + r) * 256 + c2] = acc[nt][r] + b;
        }
    }
}

// ---------------------------------------------------------------------------
// 27-neighbor attention, float4. 32 threads/voxel, 8 voxels/block.
// Emits ao as bf16 hi/lo split for the MFMA projection.
// ---------------------------------------------------------------------------
__global__ __launch_bounds__(256) void attn3d(
    const float4* __restrict__ qb4, const float4* __restrict__ kvb4,
    ushort4* __restrict__ aoh, ushort4* __restrict__ aol)
{
    const int t   = threadIdx.x;
    const int n   = blockIdx.x * 8 + (t >> 5);
    const int sub = t & 31;

    const int w = n % DD3;
    const int h = (n / DD3) % DD3;
    const int d = n / (DD3 * DD3);

    const float4 q = qb4[n * 32 + sub];

    int   nb[27];
    float logit[27];

    #pragma unroll
    for (int idx = 0; idx < 27; ++idx) {
        const int i = idx / 9, j = (idx / 3) % 3, l = idx % 3;
        const int dd = d + i - 1, hh = h + j - 1, ww = w + l - 1;
        const bool ok = (unsigned)dd < DD3 && (unsigned)hh < DD3 && (unsigned)ww < DD3;
        nb[idx] = ok ? ((dd * DD3 + hh) * DD3 + ww) * 64 : -1;
    }

    #pragma unroll
    for (int idx = 0; idx < 27; ++idx) {
        float p = 0.f;
        if (nb[idx] >= 0) {
            const float4 kk = kvb4[nb[idx] + sub];
            p = q.x * kk.x + q.y * kk.y + q.z * kk.z + q.w * kk.w;
        }
        p += __shfl_xor(p, 1);
        p += __shfl_xor(p, 2);
        p += __shfl_xor(p, 4);
        logit[idx] = p;   // exactly 0 for OOB (reference pads kv with zeros)
    }

    float mx = logit[0];
    #pragma unroll
    for (int idx = 1; idx < 27; ++idx) mx = fmaxf(mx, logit[idx]);
    float s = 0.f;
    #pragma unroll
    for (int idx = 0; idx < 27; ++idx) {
        logit[idx] = __expf(logit[idx] - mx);
        s += logit[idx];
    }
    const float inv = 1.f / s;

    float4 acc = {0.f, 0.f, 0.f, 0.f};
    #pragma unroll
    for (int idx = 0; idx < 27; ++idx) {
        if (nb[idx] >= 0) {
            const float4 vv = kvb4[nb[idx] + 32 + sub];
            acc.x += logit[idx] * vv.x;
            acc.y += logit[idx] * vv.y;
            acc.z += logit[idx] * vv.z;
            acc.w += logit[idx] * vv.w;
        }
    }
    acc.x *= inv; acc.y *= inv; acc.z *= inv; acc.w *= inv;

    ushort4 hh4, ll4;
    hh4.x = bf16_rtn(acc.x); ll4.x = bf16_rtn(acc.x - bf16_f32(hh4.x));
    hh4.y = bf16_rtn(acc.y); ll4.y = bf16_rtn(acc.y - bf16_f32(hh4.y));
    hh4.z = bf16_rtn(acc.z); ll4.z = bf16_rtn(acc.z - bf16_f32(hh4.z));
    hh4.w = bf16_rtn(acc.w); ll4.w = bf16_rtn(acc.w - bf16_f32(hh4.w));
    aoh[n * 32 + sub] = hh4;
    aol[n * 32 + sub] = ll4;
}

// ---------------------------------------------------------------------------
// Split-bf16 MFMA projection: ao[N][128] @ Wp + bp -> out f32.
// wt rows 384..511.  grid = (216, 2).
// ---------------------------------------------------------------------------
__global__ __launch_bounds__(256) void proj_mfma(
    const ushort* __restrict__ aoh, const ushort* __restrict__ aol,
    const ushort* __restrict__ wth, const ushort* __restrict__ wtl,
    const float* __restrict__ bp, float* __restrict__ out)
{
    const int t  = threadIdx.x;
    const int wv = t >> 6, l = t & 63;
    const int lm = l & 15, lk = l >> 4;
    const int row = blockIdx.x * 64 + wv * 16 + lm;
    const int n0  = blockIdx.y * 64;
    const int ko  = lk * 8;

    f32x4 acc[4];
    #pragma unroll
    for (int nt = 0; nt < 4; ++nt)
        #pragma unroll
        for (int r = 0; r < 4; ++r) acc[nt][r] = 0.f;

    #pragma unroll
    for (int kb = 0; kb < 4; ++kb) {
        const int k0 = kb * 32;
        const s16x8 ah = *(const s16x8*)(aoh + row * 128 + k0 + ko);
        const s16x8 al = *(const s16x8*)(aol + row * 128 + k0 + ko);
        #pragma unroll
        for (int nt = 0; nt < 4; ++nt) {
            const int wr = 384 + n0 + nt * 16 + lm;
            const s16x8 bh = *(const s16x8*)(wth + wr * 128 + k0 + ko);
            const s16x8 bl = *(const s16x8*)(wtl + wr * 128 + k0 + ko);
            acc[nt] = __builtin_amdgcn_mfma_f32_16x16x32_bf16(ah, bh, acc[nt], 0, 0, 0);
            acc[nt] = __builtin_amdgcn_mfma_f32_16x16x32_bf16(ah, bl, acc[nt], 0, 0, 0);
            acc[nt] = __builtin_amdgcn_mfma_f32_16x16x32_bf16(al, bh, acc[nt], 0, 0, 0);
        }
    }

    const int orow0 = blockIdx.x * 64 + wv * 16 + lk * 4;
    #pragma unroll
    for (int nt = 0; nt < 4; ++nt) {
        const int col = n0 + nt * 16 + lm;
        const float b = bp[col];
        #pragma unroll
        for (int r = 0; r < 4; ++r)
            out[(orow0 + r) * 128 + col] = acc[nt][r] + b;
    }
}

extern "C" void kernel_launch(void* const* d_in, const int* in_sizes, int n_in,
                              void* d_out, int out_size, void* d_ws, size_t ws_size,
                              hipStream_t stream) {
    const float* x   = (const float*)d_in[0];
    const float* Wq  = (const float*)d_in[1];
    const float* bq  = (const float*)d_in[2];
    const float* Wkv = (const float*)d_in[3];
    const float* bkv = (const float*)d_in[4];
    const float* Wp  = (const float*)d_in[5];
    const float* bp  = (const float*)d_in[6];
    float* out = (float*)d_out;

    // workspace layout (bytes):
    //   qb   f32  N*128          @ 0            (7,077,888)
    //   kvb  f32  N*256          @ 7,077,888    (14,155,776)
    //   xh   u16  N*128          @ 21,233,664   (3,538,944)   (reused as ao_hi)
    //   xl   u16  N*128          @ 24,772,608   (3,538,944)   (reused as ao_lo)
    //   wth  u16  512*128        @ 28,311,552   (131,072)
    //   wtl  u16  512*128        @ 28,442,624   (131,072)
    char* ws = (char*)d_ws;
    float*  qb  = (float*)(ws);
    float*  kvb = (float*)(ws + 7077888);
    ushort* xh  = (ushort*)(ws + 21233664);
    ushort* xl  = (ushort*)(ws + 24772608);
    ushort* wth = (ushort*)(ws + 28311552);
    ushort* wtl = (ushort*)(ws + 28442624);

    prep_w<<<64, 256, 0, stream>>>(Wq, Wkv, Wp, wth, wtl);
    prep_x<<<NTOK * CCH / 4 / 256, 256, 0, stream>>>((const float4*)x,
                                                     (ushort4*)xh, (ushort4*)xl);
    dim3 g1(NTOK / 64, 6);
    qkv_mfma<<<g1, 256, 0, stream>>>(xh, xl, wth, wtl, bq, bkv, qb, kvb);
    attn3d<<<NTOK / 8, 256, 0, stream>>>((const float4*)qb, (const float4*)kvb,
                                         (ushort4*)xh, (ushort4*)xl);
    dim3 g2(NTOK / 64, 2);
    proj_mfma<<<g2, 256, 0, stream>>>(xh, xl, wth, wtl, bp, out);
}

// Round 6
// 89.206 us; speedup vs baseline: 1.6512x; 1.0309x over previous
//
#include <hip/hip_runtime.h>
#include <math.h>

// Problem constants: B=1, D=H=W=24, N=13824, C=128, NUM_HEADS=4, hc=32, K3=27.
#define NTOK 13824
#define CCH 128
#define DD3 24
#define SCALE 0.17677669529663687f  // 32^-0.5

typedef float  f32x4  __attribute__((ext_vector_type(4)));
typedef short  s16x8  __attribute__((ext_vector_type(8)));

__device__ __forceinline__ ushort bf16_rtn(float f) {
    unsigned u = __float_as_uint(f);
    unsigned r = u + 0x7fffu + ((u >> 16) & 1u);
    return (ushort)(r >> 16);
}
__device__ __forceinline__ float bf16_f32(ushort h) {
    return __uint_as_float(((unsigned)h) << 16);
}
__device__ __forceinline__ float4 bf4_f4(ushort4 u) {
    float4 f;
    f.x = bf16_f32(u.x); f.y = bf16_f32(u.y);
    f.z = bf16_f32(u.z); f.w = bf16_f32(u.w);
    return f;
}

// ---------------------------------------------------------------------------
// prep_w: transpose + split all three weight mats into wt[512][128] bf16 hi/lo.
// rows 0-127: Wq cols; 128-383: Wkv cols; 384-511: Wp cols.  wt[n][k] = W[k][n].
// ---------------------------------------------------------------------------
__global__ __launch_bounds__(256) void prep_w(
    const float* __restrict__ Wq, const float* __restrict__ Wkv,
    const float* __restrict__ Wp,
    ushort* __restrict__ wth, ushort* __restrict__ wtl)
{
    const int i  = blockIdx.x * 256 + threadIdx.x;  // 0..16383
    const int rr = i >> 5;                          // 0..511
    const int k4 = (i & 31) * 4;
    const float* W; int col, ldw;
    if (rr < 128)      { W = Wq;  col = rr;       ldw = 128; }
    else if (rr < 384) { W = Wkv; col = rr - 128; ldw = 256; }
    else               { W = Wp;  col = rr - 384; ldw = 128; }
    #pragma unroll
    for (int j = 0; j < 4; ++j) {
        float v = W[(k4 + j) * ldw + col];
        ushort h = bf16_rtn(v);
        wth[rr * 128 + k4 + j] = h;
        wtl[rr * 128 + k4 + j] = bf16_rtn(v - bf16_f32(h));
    }
}

// ---------------------------------------------------------------------------
// Split-bf16 MFMA GEMM for QKV, x converted to bf16 hi/lo in registers.
// block = 256 thr (4 waves); tile 64 rows x 64 cols; grid = (216, 6).
// cols 0-127 -> qb f32 (scaled); cols 128-383 -> kvb bf16.
// ---------------------------------------------------------------------------
__global__ __launch_bounds__(256) void qkv_mfma(
    const float* __restrict__ x,
    const ushort* __restrict__ wth, const ushort* __restrict__ wtl,
    const float* __restrict__ bq, const float* __restrict__ bkv,
    float* __restrict__ qb, ushort* __restrict__ kvb)
{
    const int t  = threadIdx.x;
    const int wv = t >> 6, l = t & 63;
    const int lm = l & 15, lk = l >> 4;
    const int row = blockIdx.x * 64 + wv * 16 + lm;   // A row for this lane
    const int n0  = blockIdx.y * 64;                  // output col base
    const int ko  = lk * 8;

    f32x4 acc[4];
    #pragma unroll
    for (int nt = 0; nt < 4; ++nt)
        #pragma unroll
        for (int r = 0; r < 4; ++r) acc[nt][r] = 0.f;

    #pragma unroll
    for (int kb = 0; kb < 4; ++kb) {
        const int k0 = kb * 32;
        const float4 a0 = *(const float4*)(x + row * 128 + k0 + ko);
        const float4 a1 = *(const float4*)(x + row * 128 + k0 + ko + 4);
        const float av[8] = {a0.x, a0.y, a0.z, a0.w, a1.x, a1.y, a1.z, a1.w};
        s16x8 ah, al;
        #pragma unroll
        for (int e = 0; e < 8; ++e) {
            ushort hh = bf16_rtn(av[e]);
            ah[e] = (short)hh;
            al[e] = (short)bf16_rtn(av[e] - bf16_f32(hh));
        }
        #pragma unroll
        for (int nt = 0; nt < 4; ++nt) {
            const int wr = n0 + nt * 16 + lm;
            const s16x8 bh = *(const s16x8*)(wth + wr * 128 + k0 + ko);
            const s16x8 bl = *(const s16x8*)(wtl + wr * 128 + k0 + ko);
            acc[nt] = __builtin_amdgcn_mfma_f32_16x16x32_bf16(ah, bh, acc[nt], 0, 0, 0);
            acc[nt] = __builtin_amdgcn_mfma_f32_16x16x32_bf16(ah, bl, acc[nt], 0, 0, 0);
            acc[nt] = __builtin_amdgcn_mfma_f32_16x16x32_bf16(al, bh, acc[nt], 0, 0, 0);
        }
    }

    const int orow0 = blockIdx.x * 64 + wv * 16 + lk * 4;
    #pragma unroll
    for (int nt = 0; nt < 4; ++nt) {
        const int col = n0 + nt * 16 + lm;
        if (col < 128) {
            const float b = bq[col];
            #pragma unroll
            for (int r = 0; r < 4; ++r)
                qb[(orow0 + r) * 128 + col] = (acc[nt][r] + b) * SCALE;
        } else {
            const int c2 = col - 128;
            const float b = bkv[c2];
            #pragma unroll
            for (int r = 0; r < 4; ++r)
                kvb[(orow0 + r) * 256 + c2] = bf16_rtn(acc[nt][r] + b);
        }
    }
}

// ---------------------------------------------------------------------------
// 27-neighbor attention; kv in bf16 (ushort4 = 4 channels, 8B loads).
// 32 threads/voxel, 8 voxels per 256-thread block.
// Head = sub>>3; 8 lanes/head reduce via __shfl_xor 1,2,4.
// OOB neighbors: logit = 0 (reference pads kv with zeros), v = 0.
// Emits ao as bf16 hi/lo split for the MFMA projection.
// ---------------------------------------------------------------------------
__global__ __launch_bounds__(256) void attn3d(
    const float4* __restrict__ qb4, const ushort4* __restrict__ kvb4,
    ushort4* __restrict__ aoh, ushort4* __restrict__ aol)
{
    const int t   = threadIdx.x;
    const int n   = blockIdx.x * 8 + (t >> 5);
    const int sub = t & 31;

    const int w = n % DD3;
    const int h = (n / DD3) % DD3;
    const int d = n / (DD3 * DD3);

    const float4 q = qb4[n * 32 + sub];

    int   nb[27];     // neighbor base index into kvb4 (4-ch units), -1 if OOB
    float logit[27];

    #pragma unroll
    for (int idx = 0; idx < 27; ++idx) {
        const int i = idx / 9, j = (idx / 3) % 3, l = idx % 3;
        const int dd = d + i - 1, hh = h + j - 1, ww = w + l - 1;
        const bool ok = (unsigned)dd < DD3 && (unsigned)hh < DD3 && (unsigned)ww < DD3;
        nb[idx] = ok ? ((dd * DD3 + hh) * DD3 + ww) * 64 : -1;
    }

    #pragma unroll
    for (int idx = 0; idx < 27; ++idx) {
        float p = 0.f;
        if (nb[idx] >= 0) {
            const float4 kk = bf4_f4(kvb4[nb[idx] + sub]);
            p = q.x * kk.x + q.y * kk.y + q.z * kk.z + q.w * kk.w;
        }
        p += __shfl_xor(p, 1);
        p += __shfl_xor(p, 2);
        p += __shfl_xor(p, 4);
        logit[idx] = p;   // exactly 0 for OOB
    }

    float mx = logit[0];
    #pragma unroll
    for (int idx = 1; idx < 27; ++idx) mx = fmaxf(mx, logit[idx]);
    float s = 0.f;
    #pragma unroll
    for (int idx = 0; idx < 27; ++idx) {
        logit[idx] = __expf(logit[idx] - mx);
        s += logit[idx];
    }
    const float inv = 1.f / s;

    float4 acc = {0.f, 0.f, 0.f, 0.f};
    #pragma unroll
    for (int idx = 0; idx < 27; ++idx) {
        if (nb[idx] >= 0) {
            const float4 vv = bf4_f4(kvb4[nb[idx] + 32 + sub]);
            acc.x += logit[idx] * vv.x;
            acc.y += logit[idx] * vv.y;
            acc.z += logit[idx] * vv.z;
            acc.w += logit[idx] * vv.w;
        }
    }
    acc.x *= inv; acc.y *= inv; acc.z *= inv; acc.w *= inv;

    ushort4 hh4, ll4;
    hh4.x = bf16_rtn(acc.x); ll4.x = bf16_rtn(acc.x - bf16_f32(hh4.x));
    hh4.y = bf16_rtn(acc.y); ll4.y = bf16_rtn(acc.y - bf16_f32(hh4.y));
    hh4.z = bf16_rtn(acc.z); ll4.z = bf16_rtn(acc.z - bf16_f32(hh4.z));
    hh4.w = bf16_rtn(acc.w); ll4.w = bf16_rtn(acc.w - bf16_f32(hh4.w));
    aoh[n * 32 + sub] = hh4;
    aol[n * 32 + sub] = ll4;
}

// ---------------------------------------------------------------------------
// Split-bf16 MFMA projection: ao[N][128] @ Wp + bp -> out f32.
// wt rows 384..511.  grid = (216, 2).
// ---------------------------------------------------------------------------
__global__ __launch_bounds__(256) void proj_mfma(
    const ushort* __restrict__ aoh, const ushort* __restrict__ aol,
    const ushort* __restrict__ wth, const ushort* __restrict__ wtl,
    const float* __restrict__ bp, float* __restrict__ out)
{
    const int t  = threadIdx.x;
    const int wv = t >> 6, l = t & 63;
    const int lm = l & 15, lk = l >> 4;
    const int row = blockIdx.x * 64 + wv * 16 + lm;
    const int n0  = blockIdx.y * 64;
    const int ko  = lk * 8;

    f32x4 acc[4];
    #pragma unroll
    for (int nt = 0; nt < 4; ++nt)
        #pragma unroll
        for (int r = 0; r < 4; ++r) acc[nt][r] = 0.f;

    #pragma unroll
    for (int kb = 0; kb < 4; ++kb) {
        const int k0 = kb * 32;
        const s16x8 ah = *(const s16x8*)(aoh + row * 128 + k0 + ko);
        const s16x8 al = *(const s16x8*)(aol + row * 128 + k0 + ko);
        #pragma unroll
        for (int nt = 0; nt < 4; ++nt) {
            const int wr = 384 + n0 + nt * 16 + lm;
            const s16x8 bh = *(const s16x8*)(wth + wr * 128 + k0 + ko);
            const s16x8 bl = *(const s16x8*)(wtl + wr * 128 + k0 + ko);
            acc[nt] = __builtin_amdgcn_mfma_f32_16x16x32_bf16(ah, bh, acc[nt], 0, 0, 0);
            acc[nt] = __builtin_amdgcn_mfma_f32_16x16x32_bf16(ah, bl, acc[nt], 0, 0, 0);
            acc[nt] = __builtin_amdgcn_mfma_f32_16x16x32_bf16(al, bh, acc[nt], 0, 0, 0);
        }
    }

    const int orow0 = blockIdx.x * 64 + wv * 16 + lk * 4;
    #pragma unroll
    for (int nt = 0; nt < 4; ++nt) {
        const int col = n0 + nt * 16 + lm;
        const float b = bp[col];
        #pragma unroll
        for (int r = 0; r < 4; ++r)
            out[(orow0 + r) * 128 + col] = acc[nt][r] + b;
    }
}

extern "C" void kernel_launch(void* const* d_in, const int* in_sizes, int n_in,
                              void* d_out, int out_size, void* d_ws, size_t ws_size,
                              hipStream_t stream) {
    const float* x   = (const float*)d_in[0];
    const float* Wq  = (const float*)d_in[1];
    const float* bq  = (const float*)d_in[2];
    const float* Wkv = (const float*)d_in[3];
    const float* bkv = (const float*)d_in[4];
    const float* Wp  = (const float*)d_in[5];
    const float* bp  = (const float*)d_in[6];
    float* out = (float*)d_out;

    // workspace layout (bytes):
    //   qb   f32  N*128   @ 0            (7,077,888)
    //   kvb  bf16 N*256   @ 7,077,888    (7,077,888)
    //   aoh  u16  N*128   @ 14,155,776   (3,538,944)
    //   aol  u16  N*128   @ 17,694,720   (3,538,944)
    //   wth  u16  512*128 @ 21,233,664   (131,072)
    //   wtl  u16  512*128 @ 21,364,736   (131,072)
    char* ws = (char*)d_ws;
    float*  qb  = (float*)(ws);
    ushort* kvb = (ushort*)(ws + 7077888);
    ushort* aoh = (ushort*)(ws + 14155776);
    ushort* aol = (ushort*)(ws + 17694720);
    ushort* wth = (ushort*)(ws + 21233664);
    ushort* wtl = (ushort*)(ws + 21364736);

    prep_w<<<64, 256, 0, stream>>>(Wq, Wkv, Wp, wth, wtl);
    dim3 g1(NTOK / 64, 6);
    qkv_mfma<<<g1, 256, 0, stream>>>(x, wth, wtl, bq, bkv, qb, kvb);
    attn3d<<<NTOK / 8, 256, 0, stream>>>((const float4*)qb, (const ushort4*)kvb,
                                         (ushort4*)aoh, (ushort4*)aol);
    dim3 g2(NTOK / 64, 2);
    proj_mfma<<<g2, 256, 0, stream>>>(aoh, aol, wth, wtl, bp, out);
}

// Round 7
// 66.389 us; speedup vs baseline: 2.2187x; 1.3437x over previous
//
#include <hip/hip_runtime.h>
#include <math.h>

// Problem constants: B=1, D=H=W=24, N=13824, C=128, NUM_HEADS=4, hc=32, K3=27.
#define NTOK 13824
#define CCH 128
#define DD3 24
#define SCALE 0.17677669529663687f  // 32^-0.5

typedef float  f32x4  __attribute__((ext_vector_type(4)));
typedef short  s16x8  __attribute__((ext_vector_type(8)));

__device__ __forceinline__ ushort bf16_rtn(float f) {
    unsigned u = __float_as_uint(f);
    unsigned r = u + 0x7fffu + ((u >> 16) & 1u);
    return (ushort)(r >> 16);
}
__device__ __forceinline__ float bf16_f32(ushort h) {
    return __uint_as_float(((unsigned)h) << 16);
}
__device__ __forceinline__ float4 bf4_f4(ushort4 u) {
    float4 f;
    f.x = bf16_f32(u.x); f.y = bf16_f32(u.y);
    f.z = bf16_f32(u.z); f.w = bf16_f32(u.w);
    return f;
}

// Swizzled LDS element index for B panel: row n (0..63), 8-elem k-group g (0..15).
// XOR keeps ds_read_b128 bank-balanced (8 accesses/bank = b128 minimum).
#define BSW(n, g) ((n) * 128 + ((((g) ^ ((n) & 7))) << 3))

// ---------------------------------------------------------------------------
// QKV GEMM, fused W-conversion. grid (216, 6), block 256 (4 waves).
// Block tile: 64 rows x 64 cols of the concatenated [q|k|v] (384-col) output.
// W segment converted f32 -> bf16 hi/lo into swizzled LDS once per block.
// A (x rows) converted to bf16 hi/lo in registers, loaded once.
// cols 0-127 -> qb f32 (scaled); cols 128-383 -> kvb bf16.
// ---------------------------------------------------------------------------
__global__ __launch_bounds__(256) void qkv_fused(
    const float* __restrict__ x,
    const float* __restrict__ Wq, const float* __restrict__ Wkv,
    const float* __restrict__ bq, const float* __restrict__ bkv,
    float* __restrict__ qb, ushort* __restrict__ kvb)
{
    __shared__ ushort bsh[2][64 * 128];   // [hi/lo][swizzled n*128+k]  32 KB

    const int t  = threadIdx.x;
    const int y  = blockIdx.y;            // 0..5: 64-col segment of [q|kv]
    const float* W;
    int ldw, scol;
    if (y < 2) { W = Wq;  ldw = 128; scol = y * 64; }
    else       { W = Wkv; ldw = 256; scol = (y - 2) * 64; }

    // ---- stage W segment into LDS (hi/lo split, swizzled) ----
    #pragma unroll
    for (int p = 0; p < 8; ++p) {
        const int idx  = p * 256 + t;       // 0..2047  (k 0..127) x (col4 0..15)
        const int k    = idx >> 4;
        const int col4 = (idx & 15) * 4;
        const float4 v = *(const float4*)(W + k * ldw + scol + col4);
        const float vv[4] = {v.x, v.y, v.z, v.w};
        #pragma unroll
        for (int j = 0; j < 4; ++j) {
            const int n = col4 + j;
            const int e = BSW(n, k >> 3) + (k & 7);
            const ushort hh = bf16_rtn(vv[j]);
            bsh[0][e] = hh;
            bsh[1][e] = bf16_rtn(vv[j] - bf16_f32(hh));
        }
    }

    const int wv = t >> 6, l = t & 63;
    const int lm = l & 15, lk = l >> 4;
    const int row = blockIdx.x * 64 + wv * 16 + lm;
    const int ko  = lk * 8;

    // ---- load + convert A fragments (all 4 k-blocks) ----
    s16x8 ah[4], al[4];
    #pragma unroll
    for (int kb = 0; kb < 4; ++kb) {
        const int k0 = kb * 32;
        const float4 a0 = *(const float4*)(x + row * 128 + k0 + ko);
        const float4 a1 = *(const float4*)(x + row * 128 + k0 + ko + 4);
        const float av[8] = {a0.x, a0.y, a0.z, a0.w, a1.x, a1.y, a1.z, a1.w};
        #pragma unroll
        for (int e = 0; e < 8; ++e) {
            const ushort hh = bf16_rtn(av[e]);
            ah[kb][e] = (short)hh;
            al[kb][e] = (short)bf16_rtn(av[e] - bf16_f32(hh));
        }
    }

    __syncthreads();

    f32x4 acc[4];
    #pragma unroll
    for (int nt = 0; nt < 4; ++nt)
        #pragma unroll
        for (int r = 0; r < 4; ++r) acc[nt][r] = 0.f;

    #pragma unroll
    for (int nt = 0; nt < 4; ++nt) {
        const int n = nt * 16 + lm;           // segment-local output col
        s16x8 bh[4], bl[4];
        #pragma unroll
        for (int kb = 0; kb < 4; ++kb) {
            const int g = kb * 4 + lk;
            bh[kb] = *(const s16x8*)(&bsh[0][BSW(n, g)]);
            bl[kb] = *(const s16x8*)(&bsh[1][BSW(n, g)]);
        }
        #pragma unroll
        for (int kb = 0; kb < 4; ++kb) {
            acc[nt] = __builtin_amdgcn_mfma_f32_16x16x32_bf16(ah[kb], bh[kb], acc[nt], 0, 0, 0);
            acc[nt] = __builtin_amdgcn_mfma_f32_16x16x32_bf16(ah[kb], bl[kb], acc[nt], 0, 0, 0);
            acc[nt] = __builtin_amdgcn_mfma_f32_16x16x32_bf16(al[kb], bh[kb], acc[nt], 0, 0, 0);
        }
    }

    const int orow0 = blockIdx.x * 64 + wv * 16 + lk * 4;
    #pragma unroll
    for (int nt = 0; nt < 4; ++nt) {
        const int col = y * 64 + nt * 16 + lm;   // col in [q|kv] 384
        if (col < 128) {
            const float b = bq[col];
            #pragma unroll
            for (int r = 0; r < 4; ++r)
                qb[(orow0 + r) * 128 + col] = (acc[nt][r] + b) * SCALE;
        } else {
            const int c2 = col - 128;
            const float b = bkv[c2];
            #pragma unroll
            for (int r = 0; r < 4; ++r)
                kvb[(orow0 + r) * 256 + c2] = bf16_rtn(acc[nt][r] + b);
        }
    }
}

// ---------------------------------------------------------------------------
// 27-neighbor attention; kv in bf16 (ushort4 = 4 channels, 8B loads).
// 32 threads/voxel, 8 voxels per 256-thread block.
// OOB neighbors: logit = 0 (reference pads kv with zeros), v = 0.
// Emits ao as bf16 hi/lo split for the MFMA projection.
// ---------------------------------------------------------------------------
__global__ __launch_bounds__(256) void attn3d(
    const float4* __restrict__ qb4, const ushort4* __restrict__ kvb4,
    ushort4* __restrict__ aoh, ushort4* __restrict__ aol)
{
    const int t   = threadIdx.x;
    const int n   = blockIdx.x * 8 + (t >> 5);
    const int sub = t & 31;

    const int w = n % DD3;
    const int h = (n / DD3) % DD3;
    const int d = n / (DD3 * DD3);

    const float4 q = qb4[n * 32 + sub];

    int   nb[27];
    float logit[27];

    #pragma unroll
    for (int idx = 0; idx < 27; ++idx) {
        const int i = idx / 9, j = (idx / 3) % 3, l = idx % 3;
        const int dd = d + i - 1, hh = h + j - 1, ww = w + l - 1;
        const bool ok = (unsigned)dd < DD3 && (unsigned)hh < DD3 && (unsigned)ww < DD3;
        nb[idx] = ok ? ((dd * DD3 + hh) * DD3 + ww) * 64 : -1;
    }

    #pragma unroll
    for (int idx = 0; idx < 27; ++idx) {
        float p = 0.f;
        if (nb[idx] >= 0) {
            const float4 kk = bf4_f4(kvb4[nb[idx] + sub]);
            p = q.x * kk.x + q.y * kk.y + q.z * kk.z + q.w * kk.w;
        }
        p += __shfl_xor(p, 1);
        p += __shfl_xor(p, 2);
        p += __shfl_xor(p, 4);
        logit[idx] = p;   // exactly 0 for OOB
    }

    float mx = logit[0];
    #pragma unroll
    for (int idx = 1; idx < 27; ++idx) mx = fmaxf(mx, logit[idx]);
    float s = 0.f;
    #pragma unroll
    for (int idx = 0; idx < 27; ++idx) {
        logit[idx] = __expf(logit[idx] - mx);
        s += logit[idx];
    }
    const float inv = 1.f / s;

    float4 acc = {0.f, 0.f, 0.f, 0.f};
    #pragma unroll
    for (int idx = 0; idx < 27; ++idx) {
        if (nb[idx] >= 0) {
            const float4 vv = bf4_f4(kvb4[nb[idx] + 32 + sub]);
            acc.x += logit[idx] * vv.x;
            acc.y += logit[idx] * vv.y;
            acc.z += logit[idx] * vv.z;
            acc.w += logit[idx] * vv.w;
        }
    }
    acc.x *= inv; acc.y *= inv; acc.z *= inv; acc.w *= inv;

    ushort4 hh4, ll4;
    hh4.x = bf16_rtn(acc.x); ll4.x = bf16_rtn(acc.x - bf16_f32(hh4.x));
    hh4.y = bf16_rtn(acc.y); ll4.y = bf16_rtn(acc.y - bf16_f32(hh4.y));
    hh4.z = bf16_rtn(acc.z); ll4.z = bf16_rtn(acc.z - bf16_f32(hh4.z));
    hh4.w = bf16_rtn(acc.w); ll4.w = bf16_rtn(acc.w - bf16_f32(hh4.w));
    aoh[n * 32 + sub] = hh4;
    aol[n * 32 + sub] = ll4;
}

// ---------------------------------------------------------------------------
// Projection, fused Wp-conversion. grid (216, 2), block 256.
// ao (bf16 hi/lo) [N][128] @ Wp[128][128] + bp -> out f32.
// ---------------------------------------------------------------------------
__global__ __launch_bounds__(256) void proj_fused(
    const ushort* __restrict__ aoh, const ushort* __restrict__ aol,
    const float* __restrict__ Wp, const float* __restrict__ bp,
    float* __restrict__ out)
{
    __shared__ ushort bsh[2][64 * 128];   // 32 KB

    const int t    = threadIdx.x;
    const int scol = blockIdx.y * 64;

    #pragma unroll
    for (int p = 0; p < 8; ++p) {
        const int idx  = p * 256 + t;
        const int k    = idx >> 4;
        const int col4 = (idx & 15) * 4;
        const float4 v = *(const float4*)(Wp + k * 128 + scol + col4);
        const float vv[4] = {v.x, v.y, v.z, v.w};
        #pragma unroll
        for (int j = 0; j < 4; ++j) {
            const int n = col4 + j;
            const int e = BSW(n, k >> 3) + (k & 7);
            const ushort hh = bf16_rtn(vv[j]);
            bsh[0][e] = hh;
            bsh[1][e] = bf16_rtn(vv[j] - bf16_f32(hh));
        }
    }

    const int wv = t >> 6, l = t & 63;
    const int lm = l & 15, lk = l >> 4;
    const int row = blockIdx.x * 64 + wv * 16 + lm;
    const int ko  = lk * 8;

    s16x8 ah[4], al[4];
    #pragma unroll
    for (int kb = 0; kb < 4; ++kb) {
        const int k0 = kb * 32;
        ah[kb] = *(const s16x8*)(aoh + row * 128 + k0 + ko);
        al[kb] = *(const s16x8*)(aol + row * 128 + k0 + ko);
    }

    __syncthreads();

    f32x4 acc[4];
    #pragma unroll
    for (int nt = 0; nt < 4; ++nt)
        #pragma unroll
        for (int r = 0; r < 4; ++r) acc[nt][r] = 0.f;

    #pragma unroll
    for (int nt = 0; nt < 4; ++nt) {
        const int n = nt * 16 + lm;
        s16x8 bh[4], bl[4];
        #pragma unroll
        for (int kb = 0; kb < 4; ++kb) {
            const int g = kb * 4 + lk;
            bh[kb] = *(const s16x8*)(&bsh[0][BSW(n, g)]);
            bl[kb] = *(const s16x8*)(&bsh[1][BSW(n, g)]);
        }
        #pragma unroll
        for (int kb = 0; kb < 4; ++kb) {
            acc[nt] = __builtin_amdgcn_mfma_f32_16x16x32_bf16(ah[kb], bh[kb], acc[nt], 0, 0, 0);
            acc[nt] = __builtin_amdgcn_mfma_f32_16x16x32_bf16(ah[kb], bl[kb], acc[nt], 0, 0, 0);
            acc[nt] = __builtin_amdgcn_mfma_f32_16x16x32_bf16(al[kb], bh[kb], acc[nt], 0, 0, 0);
        }
    }

    const int orow0 = blockIdx.x * 64 + wv * 16 + lk * 4;
    #pragma unroll
    for (int nt = 0; nt < 4; ++nt) {
        const int col = scol + nt * 16 + lm;
        const float b = bp[col];
        #pragma unroll
        for (int r = 0; r < 4; ++r)
            out[(orow0 + r) * 128 + col] = acc[nt][r] + b;
    }
}

extern "C" void kernel_launch(void* const* d_in, const int* in_sizes, int n_in,
                              void* d_out, int out_size, void* d_ws, size_t ws_size,
                              hipStream_t stream) {
    const float* x   = (const float*)d_in[0];
    const float* Wq  = (const float*)d_in[1];
    const float* bq  = (const float*)d_in[2];
    const float* Wkv = (const float*)d_in[3];
    const float* bkv = (const float*)d_in[4];
    const float* Wp  = (const float*)d_in[5];
    const float* bp  = (const float*)d_in[6];
    float* out = (float*)d_out;

    // workspace layout (bytes):
    //   qb   f32  N*128   @ 0            (7,077,888)
    //   kvb  bf16 N*256   @ 7,077,888    (7,077,888)
    //   aoh  u16  N*128   @ 14,155,776   (3,538,944)
    //   aol  u16  N*128   @ 17,694,720   (3,538,944)
    char* ws = (char*)d_ws;
    float*  qb  = (float*)(ws);
    ushort* kvb = (ushort*)(ws + 7077888);
    ushort* aoh = (ushort*)(ws + 14155776);
    ushort* aol = (ushort*)(ws + 17694720);

    dim3 g1(NTOK / 64, 6);
    qkv_fused<<<g1, 256, 0, stream>>>(x, Wq, Wkv, bq, bkv, qb, kvb);
    attn3d<<<NTOK / 8, 256, 0, stream>>>((const float4*)qb, (const ushort4*)kvb,
                                         (ushort4*)aoh, (ushort4*)aol);
    dim3 g2(NTOK / 64, 2);
    proj_fused<<<g2, 256, 0, stream>>>(aoh, aol, Wp, bp, out);
}

// Round 8
// 61.544 us; speedup vs baseline: 2.3934x; 1.0787x over previous
//
#include <hip/hip_runtime.h>
#include <math.h>

// Problem constants: B=1, D=H=W=24, N=13824, C=128, NUM_HEADS=4, hc=32, K3=27.
#define NTOK 13824
#define CCH 128
#define DD3 24
#define SCALE 0.17677669529663687f  // 32^-0.5

typedef float  f32x4  __attribute__((ext_vector_type(4)));
typedef short  s16x8  __attribute__((ext_vector_type(8)));

__device__ __forceinline__ ushort bf16_rtn(float f) {
    unsigned u = __float_as_uint(f);
    unsigned r = u + 0x7fffu + ((u >> 16) & 1u);
    return (ushort)(r >> 16);
}
__device__ __forceinline__ float bf16_f32(ushort h) {
    return __uint_as_float(((unsigned)h) << 16);
}
__device__ __forceinline__ float4 bf4_f4(ushort4 u) {
    float4 f;
    f.x = bf16_f32(u.x); f.y = bf16_f32(u.y);
    f.z = bf16_f32(u.z); f.w = bf16_f32(u.w);
    return f;
}

// Swizzled LDS element index for B panel: row n (0..63), 8-elem k-group g (0..15).
#define BSW(n, g) ((n) * 128 + ((((g) ^ ((n) & 7))) << 3))

// ---------------------------------------------------------------------------
// QKV GEMM, fused W-conversion. grid (216, 6), block 256 (4 waves).
// ---------------------------------------------------------------------------
__global__ __launch_bounds__(256) void qkv_fused(
    const float* __restrict__ x,
    const float* __restrict__ Wq, const float* __restrict__ Wkv,
    const float* __restrict__ bq, const float* __restrict__ bkv,
    float* __restrict__ qb, ushort* __restrict__ kvb)
{
    __shared__ ushort bsh[2][64 * 128];   // [hi/lo][swizzled n*128+k]  32 KB

    const int t  = threadIdx.x;
    const int y  = blockIdx.y;            // 0..5: 64-col segment of [q|kv]
    const float* W;
    int ldw, scol;
    if (y < 2) { W = Wq;  ldw = 128; scol = y * 64; }
    else       { W = Wkv; ldw = 256; scol = (y - 2) * 64; }

    #pragma unroll
    for (int p = 0; p < 8; ++p) {
        const int idx  = p * 256 + t;
        const int k    = idx >> 4;
        const int col4 = (idx & 15) * 4;
        const float4 v = *(const float4*)(W + k * ldw + scol + col4);
        const float vv[4] = {v.x, v.y, v.z, v.w};
        #pragma unroll
        for (int j = 0; j < 4; ++j) {
            const int n = col4 + j;
            const int e = BSW(n, k >> 3) + (k & 7);
            const ushort hh = bf16_rtn(vv[j]);
            bsh[0][e] = hh;
            bsh[1][e] = bf16_rtn(vv[j] - bf16_f32(hh));
        }
    }

    const int wv = t >> 6, l = t & 63;
    const int lm = l & 15, lk = l >> 4;
    const int row = blockIdx.x * 64 + wv * 16 + lm;
    const int ko  = lk * 8;

    s16x8 ah[4], al[4];
    #pragma unroll
    for (int kb = 0; kb < 4; ++kb) {
        const int k0 = kb * 32;
        const float4 a0 = *(const float4*)(x + row * 128 + k0 + ko);
        const float4 a1 = *(const float4*)(x + row * 128 + k0 + ko + 4);
        const float av[8] = {a0.x, a0.y, a0.z, a0.w, a1.x, a1.y, a1.z, a1.w};
        #pragma unroll
        for (int e = 0; e < 8; ++e) {
            const ushort hh = bf16_rtn(av[e]);
            ah[kb][e] = (short)hh;
            al[kb][e] = (short)bf16_rtn(av[e] - bf16_f32(hh));
        }
    }

    __syncthreads();

    f32x4 acc[4];
    #pragma unroll
    for (int nt = 0; nt < 4; ++nt)
        #pragma unroll
        for (int r = 0; r < 4; ++r) acc[nt][r] = 0.f;

    #pragma unroll
    for (int nt = 0; nt < 4; ++nt) {
        const int n = nt * 16 + lm;
        s16x8 bh[4], bl[4];
        #pragma unroll
        for (int kb = 0; kb < 4; ++kb) {
            const int g = kb * 4 + lk;
            bh[kb] = *(const s16x8*)(&bsh[0][BSW(n, g)]);
            bl[kb] = *(const s16x8*)(&bsh[1][BSW(n, g)]);
        }
        #pragma unroll
        for (int kb = 0; kb < 4; ++kb) {
            acc[nt] = __builtin_amdgcn_mfma_f32_16x16x32_bf16(ah[kb], bh[kb], acc[nt], 0, 0, 0);
            acc[nt] = __builtin_amdgcn_mfma_f32_16x16x32_bf16(ah[kb], bl[kb], acc[nt], 0, 0, 0);
            acc[nt] = __builtin_amdgcn_mfma_f32_16x16x32_bf16(al[kb], bh[kb], acc[nt], 0, 0, 0);
        }
    }

    const int orow0 = blockIdx.x * 64 + wv * 16 + lk * 4;
    #pragma unroll
    for (int nt = 0; nt < 4; ++nt) {
        const int col = y * 64 + nt * 16 + lm;
        if (col < 128) {
            const float b = bq[col];
            #pragma unroll
            for (int r = 0; r < 4; ++r)
                qb[(orow0 + r) * 128 + col] = (acc[nt][r] + b) * SCALE;
        } else {
            const int c2 = col - 128;
            const float b = bkv[c2];
            #pragma unroll
            for (int r = 0; r < 4; ++r)
                kvb[(orow0 + r) * 256 + c2] = bf16_rtn(acc[nt][r] + b);
        }
    }
}

// ---------------------------------------------------------------------------
// LDS-halo 27-neighbor attention.
// Block = 256 thr, tile = 2x4x4 voxels (d,h,w); halo = 4x6x6 = 144 kv rows.
// Halo staged in LDS (512 B/row: 256 B K bf16 + 256 B V bf16), OOB rows
// zero-filled == reference zero-padding (logit contribution 0, v 0) -> the
// 27-neighbor loop has NO bounds checks; neighbor offsets are compile-time
// DS-offset immediates (max 86*512 = 44032 < 65536).
// 32 lanes/voxel (4 ch each), 8 voxels/pass, 4 passes reusing the halo.
// ---------------------------------------------------------------------------
__global__ __launch_bounds__(256) void attn3d(
    const float4* __restrict__ qb4, const ushort4* __restrict__ kvb4,
    ushort4* __restrict__ aoh, ushort4* __restrict__ aol)
{
    __shared__ ushort4 sm[144 * 64];   // 73728 B

    const int t  = threadIdx.x;
    const int b  = blockIdx.x;         // 432 tiles: 12 x 6 x 6
    const int tw = b % 6, th = (b / 6) % 6, td = b / 36;
    const int d0 = td * 2, h0 = th * 4, w0 = tw * 4;

    // ---- stage halo (zero-fill OOB) ----
    #pragma unroll
    for (int p = 0; p < 36; ++p) {
        const int e = p * 256 + t;          // 0..9215 (8B chunks)
        const int r = e >> 6;               // halo row 0..143
        const int o = e & 63;               // ushort4 within row
        const int a = r / 36, bb = (r / 6) % 6, c = r % 6;
        const int gd = d0 - 1 + a, gh = h0 - 1 + bb, gw = w0 - 1 + c;
        ushort4 v = {0, 0, 0, 0};
        if ((unsigned)gd < DD3 && (unsigned)gh < DD3 && (unsigned)gw < DD3)
            v = kvb4[((gd * DD3 + gh) * DD3 + gw) * 64 + o];
        sm[r * 64 + o] = v;
    }
    __syncthreads();

    const int sub = t & 31;
    const int vx0 = t >> 5;                 // 0..7

    for (int pass = 0; pass < 4; ++pass) {
        const int vox = pass * 8 + vx0;     // 0..31 within tile
        const int ld = vox >> 4, lh = (vox >> 2) & 3, lw = vox & 3;
        const int gd = d0 + ld, gh = h0 + lh, gw = w0 + lw;
        const int n  = (gd * DD3 + gh) * DD3 + gw;

        const float4 q = qb4[n * 32 + sub];
        // voxel's neighbor base: halo cell (ld+i, lh+j, lw+l), i,j,l in 0..2
        const ushort4* kbase = &sm[(ld * 36 + lh * 6 + lw) * 64 + sub];

        float logit[27];
        #pragma unroll
        for (int i = 0; i < 3; ++i)
            #pragma unroll
            for (int j = 0; j < 3; ++j)
                #pragma unroll
                for (int l = 0; l < 3; ++l) {
                    const int idx = (i * 3 + j) * 3 + l;
                    const float4 kk = bf4_f4(kbase[(i * 36 + j * 6 + l) * 64]);
                    float p = q.x * kk.x + q.y * kk.y + q.z * kk.z + q.w * kk.w;
                    p += __shfl_xor(p, 1);
                    p += __shfl_xor(p, 2);
                    p += __shfl_xor(p, 4);
                    logit[idx] = p;
                }

        float mx = logit[0];
        #pragma unroll
        for (int idx = 1; idx < 27; ++idx) mx = fmaxf(mx, logit[idx]);
        float s = 0.f;
        #pragma unroll
        for (int idx = 0; idx < 27; ++idx) {
            logit[idx] = __expf(logit[idx] - mx);
            s += logit[idx];
        }
        const float inv = 1.f / s;

        float4 acc = {0.f, 0.f, 0.f, 0.f};
        #pragma unroll
        for (int i = 0; i < 3; ++i)
            #pragma unroll
            for (int j = 0; j < 3; ++j)
                #pragma unroll
                for (int l = 0; l < 3; ++l) {
                    const int idx = (i * 3 + j) * 3 + l;
                    const float4 vv = bf4_f4(kbase[(i * 36 + j * 6 + l) * 64 + 32]);
                    acc.x += logit[idx] * vv.x;
                    acc.y += logit[idx] * vv.y;
                    acc.z += logit[idx] * vv.z;
                    acc.w += logit[idx] * vv.w;
                }
        acc.x *= inv; acc.y *= inv; acc.z *= inv; acc.w *= inv;

        ushort4 hh4, ll4;
        hh4.x = bf16_rtn(acc.x); ll4.x = bf16_rtn(acc.x - bf16_f32(hh4.x));
        hh4.y = bf16_rtn(acc.y); ll4.y = bf16_rtn(acc.y - bf16_f32(hh4.y));
        hh4.z = bf16_rtn(acc.z); ll4.z = bf16_rtn(acc.z - bf16_f32(hh4.z));
        hh4.w = bf16_rtn(acc.w); ll4.w = bf16_rtn(acc.w - bf16_f32(hh4.w));
        aoh[n * 32 + sub] = hh4;
        aol[n * 32 + sub] = ll4;
    }
}

// ---------------------------------------------------------------------------
// Projection, fused Wp-conversion. grid (216, 2), block 256.
// ---------------------------------------------------------------------------
__global__ __launch_bounds__(256) void proj_fused(
    const ushort* __restrict__ aoh, const ushort* __restrict__ aol,
    const float* __restrict__ Wp, const float* __restrict__ bp,
    float* __restrict__ out)
{
    __shared__ ushort bsh[2][64 * 128];   // 32 KB

    const int t    = threadIdx.x;
    const int scol = blockIdx.y * 64;

    #pragma unroll
    for (int p = 0; p < 8; ++p) {
        const int idx  = p * 256 + t;
        const int k    = idx >> 4;
        const int col4 = (idx & 15) * 4;
        const float4 v = *(const float4*)(Wp + k * 128 + scol + col4);
        const float vv[4] = {v.x, v.y, v.z, v.w};
        #pragma unroll
        for (int j = 0; j < 4; ++j) {
            const int n = col4 + j;
            const int e = BSW(n, k >> 3) + (k & 7);
            const ushort hh = bf16_rtn(vv[j]);
            bsh[0][e] = hh;
            bsh[1][e] = bf16_rtn(vv[j] - bf16_f32(hh));
        }
    }

    const int wv = t >> 6, l = t & 63;
    const int lm = l & 15, lk = l >> 4;
    const int row = blockIdx.x * 64 + wv * 16 + lm;
    const int ko  = lk * 8;

    s16x8 ah[4], al[4];
    #pragma unroll
    for (int kb = 0; kb < 4; ++kb) {
        const int k0 = kb * 32;
        ah[kb] = *(const s16x8*)(aoh + row * 128 + k0 + ko);
        al[kb] = *(const s16x8*)(aol + row * 128 + k0 + ko);
    }

    __syncthreads();

    f32x4 acc[4];
    #pragma unroll
    for (int nt = 0; nt < 4; ++nt)
        #pragma unroll
        for (int r = 0; r < 4; ++r) acc[nt][r] = 0.f;

    #pragma unroll
    for (int nt = 0; nt < 4; ++nt) {
        const int n = nt * 16 + lm;
        s16x8 bh[4], bl[4];
        #pragma unroll
        for (int kb = 0; kb < 4; ++kb) {
            const int g = kb * 4 + lk;
            bh[kb] = *(const s16x8*)(&bsh[0][BSW(n, g)]);
            bl[kb] = *(const s16x8*)(&bsh[1][BSW(n, g)]);
        }
        #pragma unroll
        for (int kb = 0; kb < 4; ++kb) {
            acc[nt] = __builtin_amdgcn_mfma_f32_16x16x32_bf16(ah[kb], bh[kb], acc[nt], 0, 0, 0);
            acc[nt] = __builtin_amdgcn_mfma_f32_16x16x32_bf16(ah[kb], bl[kb], acc[nt], 0, 0, 0);
            acc[nt] = __builtin_amdgcn_mfma_f32_16x16x32_bf16(al[kb], bh[kb], acc[nt], 0, 0, 0);
        }
    }

    const int orow0 = blockIdx.x * 64 + wv * 16 + lk * 4;
    #pragma unroll
    for (int nt = 0; nt < 4; ++nt) {
        const int col = scol + nt * 16 + lm;
        const float b = bp[col];
        #pragma unroll
        for (int r = 0; r < 4; ++r)
            out[(orow0 + r) * 128 + col] = acc[nt][r] + b;
    }
}

extern "C" void kernel_launch(void* const* d_in, const int* in_sizes, int n_in,
                              void* d_out, int out_size, void* d_ws, size_t ws_size,
                              hipStream_t stream) {
    const float* x   = (const float*)d_in[0];
    const float* Wq  = (const float*)d_in[1];
    const float* bq  = (const float*)d_in[2];
    const float* Wkv = (const float*)d_in[3];
    const float* bkv = (const float*)d_in[4];
    const float* Wp  = (const float*)d_in[5];
    const float* bp  = (const float*)d_in[6];
    float* out = (float*)d_out;

    char* ws = (char*)d_ws;
    float*  qb  = (float*)(ws);                 // f32  N*128
    ushort* kvb = (ushort*)(ws + 7077888);      // bf16 N*256
    ushort* aoh = (ushort*)(ws + 14155776);     // u16  N*128
    ushort* aol = (ushort*)(ws + 17694720);     // u16  N*128

    dim3 g1(NTOK / 64, 6);
    qkv_fused<<<g1, 256, 0, stream>>>(x, Wq, Wkv, bq, bkv, qb, kvb);
    attn3d<<<432, 256, 0, stream>>>((const float4*)qb, (const ushort4*)kvb,
                                    (ushort4*)aoh, (ushort4*)aol);
    dim3 g2(NTOK / 64, 2);
    proj_fused<<<g2, 256, 0, stream>>>(aoh, aol, Wp, bp, out);
}

// Round 9
// 58.732 us; speedup vs baseline: 2.5080x; 1.0479x over previous
//
#include <hip/hip_runtime.h>
#include <math.h>

// Problem constants: B=1, D=H=W=24, N=13824, C=128, NUM_HEADS=4, hc=32, K3=27.
#define NTOK 13824
#define CCH 128
#define DD3 24
#define SCALE 0.17677669529663687f  // 32^-0.5

typedef float  f32x4  __attribute__((ext_vector_type(4)));
typedef short  s16x8  __attribute__((ext_vector_type(8)));

__device__ __forceinline__ ushort bf16_rtn(float f) {
    unsigned u = __float_as_uint(f);
    unsigned r = u + 0x7fffu + ((u >> 16) & 1u);
    return (ushort)(r >> 16);
}
__device__ __forceinline__ float bf16_f32(ushort h) {
    return __uint_as_float(((unsigned)h) << 16);
}
__device__ __forceinline__ float4 bf4_f4(ushort4 u) {
    float4 f;
    f.x = bf16_f32(u.x); f.y = bf16_f32(u.y);
    f.z = bf16_f32(u.z); f.w = bf16_f32(u.w);
    return f;
}

// Swizzled LDS element index for B panel: row n (0..63), 8-elem k-group g (0..15).
#define BSW(n, g) ((n) * 128 + ((((g) ^ ((n) & 7))) << 3))

// ---------------------------------------------------------------------------
// prep: build (a) wimg — the exact per-block LDS byte image of every weight
// segment (8 segments x [hi|lo] x 64 cols x 128 k, swizzled), (b) xh/xl —
// bf16 hi/lo split of x. W-part: blocks 0..63; x-part: blocks 64..927.
// ---------------------------------------------------------------------------
__global__ __launch_bounds__(256) void prep(
    const float* __restrict__ Wq, const float* __restrict__ Wkv,
    const float* __restrict__ Wp, const float* __restrict__ x,
    ushort* __restrict__ wimg, ushort* __restrict__ xh, ushort* __restrict__ xl)
{
    const int b = blockIdx.x;
    if (b < 64) {
        const int i   = b * 256 + threadIdx.x;   // 0..16383
        const int seg = i >> 11;                 // 0..7
        const int r   = i & 2047;
        const int n   = r & 63;                  // col within segment (coalesced)
        const int k4  = (r >> 6) * 4;            // 0..124
        const float* W; int ldw, scol;
        if (seg < 2)      { W = Wq;  ldw = 128; scol = seg * 64; }
        else if (seg < 6) { W = Wkv; ldw = 256; scol = (seg - 2) * 64; }
        else              { W = Wp;  ldw = 128; scol = (seg - 6) * 64; }
        ushort4 hi, lo;
        float v;
        v = W[(k4 + 0) * ldw + scol + n]; hi.x = bf16_rtn(v); lo.x = bf16_rtn(v - bf16_f32(hi.x));
        v = W[(k4 + 1) * ldw + scol + n]; hi.y = bf16_rtn(v); lo.y = bf16_rtn(v - bf16_f32(hi.y));
        v = W[(k4 + 2) * ldw + scol + n]; hi.z = bf16_rtn(v); lo.z = bf16_rtn(v - bf16_f32(hi.z));
        v = W[(k4 + 3) * ldw + scol + n]; hi.w = bf16_rtn(v); lo.w = bf16_rtn(v - bf16_f32(hi.w));
        const int g = k4 >> 3;
        const int f = seg * 16384 + BSW(n, g) + (k4 & 7);
        *(ushort4*)(wimg + f)        = hi;   // hi plane
        *(ushort4*)(wimg + f + 8192) = lo;   // lo plane
    } else {
        const int i = (b - 64) * 256 + threadIdx.x;   // 0..221183, 8 vals each
        const float4 a0 = ((const float4*)x)[i * 2];
        const float4 a1 = ((const float4*)x)[i * 2 + 1];
        const float av[8] = {a0.x, a0.y, a0.z, a0.w, a1.x, a1.y, a1.z, a1.w};
        ushort4 h0, h1, l0, l1;
        h0.x = bf16_rtn(av[0]); l0.x = bf16_rtn(av[0] - bf16_f32(h0.x));
        h0.y = bf16_rtn(av[1]); l0.y = bf16_rtn(av[1] - bf16_f32(h0.y));
        h0.z = bf16_rtn(av[2]); l0.z = bf16_rtn(av[2] - bf16_f32(h0.z));
        h0.w = bf16_rtn(av[3]); l0.w = bf16_rtn(av[3] - bf16_f32(h0.w));
        h1.x = bf16_rtn(av[4]); l1.x = bf16_rtn(av[4] - bf16_f32(h1.x));
        h1.y = bf16_rtn(av[5]); l1.y = bf16_rtn(av[5] - bf16_f32(h1.y));
        h1.z = bf16_rtn(av[6]); l1.z = bf16_rtn(av[6] - bf16_f32(h1.z));
        h1.w = bf16_rtn(av[7]); l1.w = bf16_rtn(av[7] - bf16_f32(h1.w));
        ((ushort4*)xh)[i * 2]     = h0;
        ((ushort4*)xh)[i * 2 + 1] = h1;
        ((ushort4*)xl)[i * 2]     = l0;
        ((ushort4*)xl)[i * 2 + 1] = l1;
    }
}

// ---------------------------------------------------------------------------
// QKV GEMM. grid (216, 6), block 256 (4 waves). W panel DMA'd from wimg via
// global_load_lds (16B); A = pre-split xh/xl. Tile 64 rows x 64 cols.
// cols 0-127 -> qb f32 (scaled); cols 128-383 -> kvb bf16.
// ---------------------------------------------------------------------------
__global__ __launch_bounds__(256) void qkv_fused(
    const ushort* __restrict__ xh, const ushort* __restrict__ xl,
    const ushort* __restrict__ wimg,
    const float* __restrict__ bq, const float* __restrict__ bkv,
    float* __restrict__ qb, ushort* __restrict__ kvb)
{
    __shared__ ushort bsh[2][8192];   // [hi/lo][swizzled n*128+k]  32 KB

    const int t  = threadIdx.x;
    const int y  = blockIdx.y;
    const int wv = t >> 6, l = t & 63;

    // ---- DMA W panel: LDS linear == wimg segment bytes ----
    const char* wseg = (const char*)(wimg + y * 16384);
    #pragma unroll
    for (int p = 0; p < 8; ++p) {
        const int chunk = (wv * 8 + p) * 1024;
        __builtin_amdgcn_global_load_lds(
            (const __attribute__((address_space(1))) void*)(wseg + chunk + l * 16),
            (__attribute__((address_space(3))) void*)((char*)bsh + chunk),
            16, 0, 0);
    }

    const int lm = l & 15, lk = l >> 4;
    const int row = blockIdx.x * 64 + wv * 16 + lm;
    const int ko  = lk * 8;

    s16x8 ah[4], al[4];
    #pragma unroll
    for (int kb = 0; kb < 4; ++kb) {
        ah[kb] = *(const s16x8*)(xh + row * 128 + kb * 32 + ko);
        al[kb] = *(const s16x8*)(xl + row * 128 + kb * 32 + ko);
    }

    __syncthreads();

    f32x4 acc[4];
    #pragma unroll
    for (int nt = 0; nt < 4; ++nt)
        #pragma unroll
        for (int r = 0; r < 4; ++r) acc[nt][r] = 0.f;

    #pragma unroll
    for (int nt = 0; nt < 4; ++nt) {
        const int n = nt * 16 + lm;
        s16x8 bh[4], bl[4];
        #pragma unroll
        for (int kb = 0; kb < 4; ++kb) {
            const int g = kb * 4 + lk;
            bh[kb] = *(const s16x8*)(&bsh[0][BSW(n, g)]);
            bl[kb] = *(const s16x8*)(&bsh[1][BSW(n, g)]);
        }
        #pragma unroll
        for (int kb = 0; kb < 4; ++kb) {
            acc[nt] = __builtin_amdgcn_mfma_f32_16x16x32_bf16(ah[kb], bh[kb], acc[nt], 0, 0, 0);
            acc[nt] = __builtin_amdgcn_mfma_f32_16x16x32_bf16(ah[kb], bl[kb], acc[nt], 0, 0, 0);
            acc[nt] = __builtin_amdgcn_mfma_f32_16x16x32_bf16(al[kb], bh[kb], acc[nt], 0, 0, 0);
        }
    }

    const int orow0 = blockIdx.x * 64 + wv * 16 + lk * 4;
    #pragma unroll
    for (int nt = 0; nt < 4; ++nt) {
        const int col = y * 64 + nt * 16 + lm;
        if (col < 128) {
            const float b = bq[col];
            #pragma unroll
            for (int r = 0; r < 4; ++r)
                qb[(orow0 + r) * 128 + col] = (acc[nt][r] + b) * SCALE;
        } else {
            const int c2 = col - 128;
            const float b = bkv[c2];
            #pragma unroll
            for (int r = 0; r < 4; ++r)
                kvb[(orow0 + r) * 256 + c2] = bf16_rtn(acc[nt][r] + b);
        }
    }
}

// ---------------------------------------------------------------------------
// LDS-halo 27-neighbor attention (unchanged from R8).
// Block = 256 thr, tile = 2x4x4 voxels; halo = 4x6x6 = 144 kv rows, zero-
// filled OOB == reference zero-padding. No bounds checks in the hot loop.
// ---------------------------------------------------------------------------
__global__ __launch_bounds__(256) void attn3d(
    const float4* __restrict__ qb4, const ushort4* __restrict__ kvb4,
    ushort4* __restrict__ aoh, ushort4* __restrict__ aol)
{
    __shared__ ushort4 sm[144 * 64];   // 73728 B

    const int t  = threadIdx.x;
    const int b  = blockIdx.x;         // 432 tiles: 12 x 6 x 6
    const int tw = b % 6, th = (b / 6) % 6, td = b / 36;
    const int d0 = td * 2, h0 = th * 4, w0 = tw * 4;

    #pragma unroll
    for (int p = 0; p < 36; ++p) {
        const int e = p * 256 + t;
        const int r = e >> 6;
        const int o = e & 63;
        const int a = r / 36, bb = (r / 6) % 6, c = r % 6;
        const int gd = d0 - 1 + a, gh = h0 - 1 + bb, gw = w0 - 1 + c;
        ushort4 v = {0, 0, 0, 0};
        if ((unsigned)gd < DD3 && (unsigned)gh < DD3 && (unsigned)gw < DD3)
            v = kvb4[((gd * DD3 + gh) * DD3 + gw) * 64 + o];
        sm[r * 64 + o] = v;
    }
    __syncthreads();

    const int sub = t & 31;
    const int vx0 = t >> 5;

    for (int pass = 0; pass < 4; ++pass) {
        const int vox = pass * 8 + vx0;
        const int ld = vox >> 4, lh = (vox >> 2) & 3, lw = vox & 3;
        const int gd = d0 + ld, gh = h0 + lh, gw = w0 + lw;
        const int n  = (gd * DD3 + gh) * DD3 + gw;

        const float4 q = qb4[n * 32 + sub];
        const ushort4* kbase = &sm[(ld * 36 + lh * 6 + lw) * 64 + sub];

        float logit[27];
        #pragma unroll
        for (int i = 0; i < 3; ++i)
            #pragma unroll
            for (int j = 0; j < 3; ++j)
                #pragma unroll
                for (int l = 0; l < 3; ++l) {
                    const int idx = (i * 3 + j) * 3 + l;
                    const float4 kk = bf4_f4(kbase[(i * 36 + j * 6 + l) * 64]);
                    float p = q.x * kk.x + q.y * kk.y + q.z * kk.z + q.w * kk.w;
                    p += __shfl_xor(p, 1);
                    p += __shfl_xor(p, 2);
                    p += __shfl_xor(p, 4);
                    logit[idx] = p;
                }

        float mx = logit[0];
        #pragma unroll
        for (int idx = 1; idx < 27; ++idx) mx = fmaxf(mx, logit[idx]);
        float s = 0.f;
        #pragma unroll
        for (int idx = 0; idx < 27; ++idx) {
            logit[idx] = __expf(logit[idx] - mx);
            s += logit[idx];
        }
        const float inv = 1.f / s;

        float4 acc = {0.f, 0.f, 0.f, 0.f};
        #pragma unroll
        for (int i = 0; i < 3; ++i)
            #pragma unroll
            for (int j = 0; j < 3; ++j)
                #pragma unroll
                for (int l = 0; l < 3; ++l) {
                    const int idx = (i * 3 + j) * 3 + l;
                    const float4 vv = bf4_f4(kbase[(i * 36 + j * 6 + l) * 64 + 32]);
                    acc.x += logit[idx] * vv.x;
                    acc.y += logit[idx] * vv.y;
                    acc.z += logit[idx] * vv.z;
                    acc.w += logit[idx] * vv.w;
                }
        acc.x *= inv; acc.y *= inv; acc.z *= inv; acc.w *= inv;

        ushort4 hh4, ll4;
        hh4.x = bf16_rtn(acc.x); ll4.x = bf16_rtn(acc.x - bf16_f32(hh4.x));
        hh4.y = bf16_rtn(acc.y); ll4.y = bf16_rtn(acc.y - bf16_f32(hh4.y));
        hh4.z = bf16_rtn(acc.z); ll4.z = bf16_rtn(acc.z - bf16_f32(hh4.z));
        hh4.w = bf16_rtn(acc.w); ll4.w = bf16_rtn(acc.w - bf16_f32(hh4.w));
        aoh[n * 32 + sub] = hh4;
        aol[n * 32 + sub] = ll4;
    }
}

// ---------------------------------------------------------------------------
// Projection. grid (216, 2), block 256. Wp panel DMA'd from wimg segs 6,7.
// ---------------------------------------------------------------------------
__global__ __launch_bounds__(256) void proj_fused(
    const ushort* __restrict__ aoh, const ushort* __restrict__ aol,
    const ushort* __restrict__ wimg,
    const float* __restrict__ bp, float* __restrict__ out)
{
    __shared__ ushort bsh[2][8192];   // 32 KB

    const int t  = threadIdx.x;
    const int wv = t >> 6, l = t & 63;

    const char* wseg = (const char*)(wimg + (6 + blockIdx.y) * 16384);
    #pragma unroll
    for (int p = 0; p < 8; ++p) {
        const int chunk = (wv * 8 + p) * 1024;
        __builtin_amdgcn_global_load_lds(
            (const __attribute__((address_space(1))) void*)(wseg + chunk + l * 16),
            (__attribute__((address_space(3))) void*)((char*)bsh + chunk),
            16, 0, 0);
    }

    const int lm = l & 15, lk = l >> 4;
    const int row = blockIdx.x * 64 + wv * 16 + lm;
    const int ko  = lk * 8;

    s16x8 ah[4], al[4];
    #pragma unroll
    for (int kb = 0; kb < 4; ++kb) {
        ah[kb] = *(const s16x8*)(aoh + row * 128 + kb * 32 + ko);
        al[kb] = *(const s16x8*)(aol + row * 128 + kb * 32 + ko);
    }

    __syncthreads();

    f32x4 acc[4];
    #pragma unroll
    for (int nt = 0; nt < 4; ++nt)
        #pragma unroll
        for (int r = 0; r < 4; ++r) acc[nt][r] = 0.f;

    #pragma unroll
    for (int nt = 0; nt < 4; ++nt) {
        const int n = nt * 16 + lm;
        s16x8 bh[4], bl[4];
        #pragma unroll
        for (int kb = 0; kb < 4; ++kb) {
            const int g = kb * 4 + lk;
            bh[kb] = *(const s16x8*)(&bsh[0][BSW(n, g)]);
            bl[kb] = *(const s16x8*)(&bsh[1][BSW(n, g)]);
        }
        #pragma unroll
        for (int kb = 0; kb < 4; ++kb) {
            acc[nt] = __builtin_amdgcn_mfma_f32_16x16x32_bf16(ah[kb], bh[kb], acc[nt], 0, 0, 0);
            acc[nt] = __builtin_amdgcn_mfma_f32_16x16x32_bf16(ah[kb], bl[kb], acc[nt], 0, 0, 0);
            acc[nt] = __builtin_amdgcn_mfma_f32_16x16x32_bf16(al[kb], bh[kb], acc[nt], 0, 0, 0);
        }
    }

    const int orow0 = blockIdx.x * 64 + wv * 16 + lk * 4;
    #pragma unroll
    for (int nt = 0; nt < 4; ++nt) {
        const int col = blockIdx.y * 64 + nt * 16 + lm;
        const float b = bp[col];
        #pragma unroll
        for (int r = 0; r < 4; ++r)
            out[(orow0 + r) * 128 + col] = acc[nt][r] + b;
    }
}

extern "C" void kernel_launch(void* const* d_in, const int* in_sizes, int n_in,
                              void* d_out, int out_size, void* d_ws, size_t ws_size,
                              hipStream_t stream) {
    const float* x   = (const float*)d_in[0];
    const float* Wq  = (const float*)d_in[1];
    const float* bq  = (const float*)d_in[2];
    const float* Wkv = (const float*)d_in[3];
    const float* bkv = (const float*)d_in[4];
    const float* Wp  = (const float*)d_in[5];
    const float* bp  = (const float*)d_in[6];
    float* out = (float*)d_out;

    // workspace layout (bytes):
    //   qb   f32  N*128   @ 0            (7,077,888)
    //   kvb  bf16 N*256   @ 7,077,888    (7,077,888)
    //   aoh  u16  N*128   @ 14,155,776   (3,538,944)
    //   aol  u16  N*128   @ 17,694,720   (3,538,944)
    //   xh   u16  N*128   @ 21,233,664   (3,538,944)
    //   xl   u16  N*128   @ 24,772,608   (3,538,944)
    //   wimg u16  8*16384 @ 28,311,552   (262,144)
    char* ws = (char*)d_ws;
    float*  qb   = (float*)(ws);
    ushort* kvb  = (ushort*)(ws + 7077888);
    ushort* aoh  = (ushort*)(ws + 14155776);
    ushort* aol  = (ushort*)(ws + 17694720);
    ushort* xh   = (ushort*)(ws + 21233664);
    ushort* xl   = (ushort*)(ws + 24772608);
    ushort* wimg = (ushort*)(ws + 28311552);

    prep<<<928, 256, 0, stream>>>(Wq, Wkv, Wp, x, wimg, xh, xl);
    dim3 g1(NTOK / 64, 6);
    qkv_fused<<<g1, 256, 0, stream>>>(xh, xl, wimg, bq, bkv, qb, kvb);
    attn3d<<<432, 256, 0, stream>>>((const float4*)qb, (const ushort4*)kvb,
                                    (ushort4*)aoh, (ushort4*)aol);
    dim3 g2(NTOK / 64, 2);
    proj_fused<<<g2, 256, 0, stream>>>(aoh, aol, wimg, bp, out);
}

// Round 10
// 58.533 us; speedup vs baseline: 2.5165x; 1.0034x over previous
//
#include <hip/hip_runtime.h>
#include <math.h>

// Problem constants: B=1, D=H=W=24, N=13824, C=128, NUM_HEADS=4, hc=32, K3=27.
#define NTOK 13824
#define CCH 128
#define DD3 24
#define SCALE 0.17677669529663687f  // 32^-0.5

typedef float  f32x4  __attribute__((ext_vector_type(4)));
typedef short  s16x8  __attribute__((ext_vector_type(8)));

__device__ __forceinline__ ushort bf16_rtn(float f) {
    unsigned u = __float_as_uint(f);
    unsigned r = u + 0x7fffu + ((u >> 16) & 1u);
    return (ushort)(r >> 16);
}
__device__ __forceinline__ float bf16_f32(ushort h) {
    return __uint_as_float(((unsigned)h) << 16);
}
__device__ __forceinline__ float4 bf4_f4(ushort4 u) {
    float4 f;
    f.x = bf16_f32(u.x); f.y = bf16_f32(u.y);
    f.z = bf16_f32(u.z); f.w = bf16_f32(u.w);
    return f;
}

// Swizzled LDS element index: row n, 8-elem k-group g (bank-balanced b128 reads)
#define BSW(n, g) ((n) * 128 + ((((g) ^ ((n) & 7))) << 3))

// ---------------------------------------------------------------------------
// prep_w: build wimg — per-block LDS byte image of all weight segments
// (8 segs x [hi 8192 | lo 8192] ushorts, swizzled). 64 blocks x 256.
// ---------------------------------------------------------------------------
__global__ __launch_bounds__(256) void prep_w(
    const float* __restrict__ Wq, const float* __restrict__ Wkv,
    const float* __restrict__ Wp, ushort* __restrict__ wimg)
{
    const int i   = blockIdx.x * 256 + threadIdx.x;   // 0..16383
    const int seg = i >> 11;                          // 0..7
    const int r   = i & 2047;
    const int n   = r & 63;                           // col within segment
    const int k4  = (r >> 6) * 4;                     // 0..124
    const float* W; int ldw, scol;
    if (seg < 2)      { W = Wq;  ldw = 128; scol = seg * 64; }
    else if (seg < 6) { W = Wkv; ldw = 256; scol = (seg - 2) * 64; }
    else              { W = Wp;  ldw = 128; scol = (seg - 6) * 64; }
    ushort4 hi, lo;
    float v;
    v = W[(k4 + 0) * ldw + scol + n]; hi.x = bf16_rtn(v); lo.x = bf16_rtn(v - bf16_f32(hi.x));
    v = W[(k4 + 1) * ldw + scol + n]; hi.y = bf16_rtn(v); lo.y = bf16_rtn(v - bf16_f32(hi.y));
    v = W[(k4 + 2) * ldw + scol + n]; hi.z = bf16_rtn(v); lo.z = bf16_rtn(v - bf16_f32(hi.z));
    v = W[(k4 + 3) * ldw + scol + n]; hi.w = bf16_rtn(v); lo.w = bf16_rtn(v - bf16_f32(hi.w));
    const int g = k4 >> 3;
    const int f = seg * 16384 + BSW(n, g) + (k4 & 7);
    *(ushort4*)(wimg + f)        = hi;
    *(ushort4*)(wimg + f + 8192) = lo;
}

// ---------------------------------------------------------------------------
// QKV GEMM. grid (216, 6), block 256 (4 waves). W panel DMA'd from wimg via
// global_load_lds (16B); A = x converted to bf16 hi/lo in registers.
// cols 0-127 -> qb f32 (scaled); cols 128-383 -> kvb bf16.
// ---------------------------------------------------------------------------
__global__ __launch_bounds__(256) void qkv_fused(
    const float* __restrict__ x, const ushort* __restrict__ wimg,
    const float* __restrict__ bq, const float* __restrict__ bkv,
    float* __restrict__ qb, ushort* __restrict__ kvb)
{
    __shared__ ushort bsh[2][8192];   // [hi/lo][swizzled n*128+k]  32 KB

    const int t  = threadIdx.x;
    const int y  = blockIdx.y;
    const int wv = t >> 6, l = t & 63;

    const char* wseg = (const char*)(wimg + y * 16384);
    #pragma unroll
    for (int p = 0; p < 8; ++p) {
        const int chunk = (wv * 8 + p) * 1024;
        __builtin_amdgcn_global_load_lds(
            (const __attribute__((address_space(1))) void*)(wseg + chunk + l * 16),
            (__attribute__((address_space(3))) void*)((char*)bsh + chunk),
            16, 0, 0);
    }

    const int lm = l & 15, lk = l >> 4;
    const int row = blockIdx.x * 64 + wv * 16 + lm;
    const int ko  = lk * 8;

    s16x8 ah[4], al[4];
    #pragma unroll
    for (int kb = 0; kb < 4; ++kb) {
        const int k0 = kb * 32;
        const float4 a0 = *(const float4*)(x + row * 128 + k0 + ko);
        const float4 a1 = *(const float4*)(x + row * 128 + k0 + ko + 4);
        const float av[8] = {a0.x, a0.y, a0.z, a0.w, a1.x, a1.y, a1.z, a1.w};
        #pragma unroll
        for (int e = 0; e < 8; ++e) {
            const ushort hh = bf16_rtn(av[e]);
            ah[kb][e] = (short)hh;
            al[kb][e] = (short)bf16_rtn(av[e] - bf16_f32(hh));
        }
    }

    __syncthreads();

    f32x4 acc[4];
    #pragma unroll
    for (int nt = 0; nt < 4; ++nt)
        #pragma unroll
        for (int r = 0; r < 4; ++r) acc[nt][r] = 0.f;

    #pragma unroll
    for (int nt = 0; nt < 4; ++nt) {
        const int n = nt * 16 + lm;
        s16x8 bh[4], bl[4];
        #pragma unroll
        for (int kb = 0; kb < 4; ++kb) {
            const int g = kb * 4 + lk;
            bh[kb] = *(const s16x8*)(&bsh[0][BSW(n, g)]);
            bl[kb] = *(const s16x8*)(&bsh[1][BSW(n, g)]);
        }
        #pragma unroll
        for (int kb = 0; kb < 4; ++kb) {
            acc[nt] = __builtin_amdgcn_mfma_f32_16x16x32_bf16(ah[kb], bh[kb], acc[nt], 0, 0, 0);
            acc[nt] = __builtin_amdgcn_mfma_f32_16x16x32_bf16(ah[kb], bl[kb], acc[nt], 0, 0, 0);
            acc[nt] = __builtin_amdgcn_mfma_f32_16x16x32_bf16(al[kb], bh[kb], acc[nt], 0, 0, 0);
        }
    }

    const int orow0 = blockIdx.x * 64 + wv * 16 + lk * 4;
    #pragma unroll
    for (int nt = 0; nt < 4; ++nt) {
        const int col = y * 64 + nt * 16 + lm;
        if (col < 128) {
            const float b = bq[col];
            #pragma unroll
            for (int r = 0; r < 4; ++r)
                qb[(orow0 + r) * 128 + col] = (acc[nt][r] + b) * SCALE;
        } else {
            const int c2 = col - 128;
            const float b = bkv[c2];
            #pragma unroll
            for (int r = 0; r < 4; ++r)
                kvb[(orow0 + r) * 256 + c2] = bf16_rtn(acc[nt][r] + b);
        }
    }
}

// ---------------------------------------------------------------------------
// Fused LDS-halo attention + projection.
// Phase 1: 2x4x4 voxel tile, 4x6x6 halo (zero-filled OOB) in LDS; 27-neighbor
//          attention, ao kept in registers (4 passes x float4 / thread).
// Phase 2: reuse LDS — DMA Wp image (64 KB, segs 6-7 of wimg) + write ao as
//          swizzled bf16 hi/lo (16 KB); 32x128 @ 128x128 MFMA; store out.
// LDS = 81920 B -> exactly 2 blocks/CU.
// ---------------------------------------------------------------------------
__global__ __launch_bounds__(256) void attn_proj(
    const float4* __restrict__ qb4, const ushort4* __restrict__ kvb4,
    const ushort* __restrict__ wimg, const float* __restrict__ bp,
    float* __restrict__ out)
{
    __shared__ ushort smem[40960];    // 81920 B
    ushort4* sm4 = (ushort4*)smem;

    const int t  = threadIdx.x;
    const int b  = blockIdx.x;         // 432 tiles: 12 x 6 x 6
    const int tw = b % 6, th = (b / 6) % 6, td = b / 36;
    const int d0 = td * 2, h0 = th * 4, w0 = tw * 4;

    // ---- phase 1: stage halo (144 rows x 512 B), zero-fill OOB ----
    #pragma unroll
    for (int p = 0; p < 36; ++p) {
        const int e = p * 256 + t;
        const int r = e >> 6;
        const int o = e & 63;
        const int a = r / 36, bb = (r / 6) % 6, c = r % 6;
        const int gd = d0 - 1 + a, gh = h0 - 1 + bb, gw = w0 - 1 + c;
        ushort4 v = {0, 0, 0, 0};
        if ((unsigned)gd < DD3 && (unsigned)gh < DD3 && (unsigned)gw < DD3)
            v = kvb4[((gd * DD3 + gh) * DD3 + gw) * 64 + o];
        sm4[r * 64 + o] = v;
    }
    __syncthreads();

    const int sub = t & 31;
    const int vx0 = t >> 5;
    float4 aov[4];

    #pragma unroll
    for (int pass = 0; pass < 4; ++pass) {
        const int vox = pass * 8 + vx0;
        const int ld = vox >> 4, lh = (vox >> 2) & 3, lw = vox & 3;
        const int n  = ((d0 + ld) * DD3 + (h0 + lh)) * DD3 + (w0 + lw);

        const float4 q = qb4[n * 32 + sub];
        const ushort4* kbase = &sm4[(ld * 36 + lh * 6 + lw) * 64 + sub];

        float logit[27];
        #pragma unroll
        for (int i = 0; i < 3; ++i)
            #pragma unroll
            for (int j = 0; j < 3; ++j)
                #pragma unroll
                for (int l2 = 0; l2 < 3; ++l2) {
                    const int idx = (i * 3 + j) * 3 + l2;
                    const float4 kk = bf4_f4(kbase[(i * 36 + j * 6 + l2) * 64]);
                    float p = q.x * kk.x + q.y * kk.y + q.z * kk.z + q.w * kk.w;
                    p += __shfl_xor(p, 1);
                    p += __shfl_xor(p, 2);
                    p += __shfl_xor(p, 4);
                    logit[idx] = p;
                }

        float mx = logit[0];
        #pragma unroll
        for (int idx = 1; idx < 27; ++idx) mx = fmaxf(mx, logit[idx]);
        float s = 0.f;
        #pragma unroll
        for (int idx = 0; idx < 27; ++idx) {
            logit[idx] = __expf(logit[idx] - mx);
            s += logit[idx];
        }
        const float inv = 1.f / s;

        float4 acc = {0.f, 0.f, 0.f, 0.f};
        #pragma unroll
        for (int i = 0; i < 3; ++i)
            #pragma unroll
            for (int j = 0; j < 3; ++j)
                #pragma unroll
                for (int l2 = 0; l2 < 3; ++l2) {
                    const int idx = (i * 3 + j) * 3 + l2;
                    const float4 vv = bf4_f4(kbase[(i * 36 + j * 6 + l2) * 64 + 32]);
                    acc.x += logit[idx] * vv.x;
                    acc.y += logit[idx] * vv.y;
                    acc.z += logit[idx] * vv.z;
                    acc.w += logit[idx] * vv.w;
                }
        aov[pass].x = acc.x * inv;
        aov[pass].y = acc.y * inv;
        aov[pass].z = acc.z * inv;
        aov[pass].w = acc.w * inv;
    }

    __syncthreads();   // all waves done reading halo

    // ---- phase 2 staging ----
    const int wv = t >> 6, l = t & 63;

    // (a) DMA Wp image: wimg segs 6,7 -> smem bytes [0, 65536)
    //     [0,16384)=s6hi  [16384,32768)=s6lo  [32768,49152)=s7hi  [49152,65536)=s7lo
    const char* wsrc = (const char*)(wimg + 6 * 16384);
    #pragma unroll
    for (int p = 0; p < 16; ++p) {
        const int chunk = (wv * 16 + p) * 1024;
        __builtin_amdgcn_global_load_lds(
            (const __attribute__((address_space(1))) void*)(wsrc + chunk + l * 16),
            (__attribute__((address_space(3))) void*)((char*)smem + chunk),
            16, 0, 0);
    }

    // (b) ao -> LDS bf16 hi/lo, swizzled. AO_H ushort idx 32768, AO_L 36864.
    #pragma unroll
    for (int p = 0; p < 4; ++p) {
        const int vox = p * 8 + vx0;
        const float4 a = aov[p];
        ushort4 hh, ll;
        hh.x = bf16_rtn(a.x); ll.x = bf16_rtn(a.x - bf16_f32(hh.x));
        hh.y = bf16_rtn(a.y); ll.y = bf16_rtn(a.y - bf16_f32(hh.y));
        hh.z = bf16_rtn(a.z); ll.z = bf16_rtn(a.z - bf16_f32(hh.z));
        hh.w = bf16_rtn(a.w); ll.w = bf16_rtn(a.w - bf16_f32(hh.w));
        const int g   = sub >> 1;
        const int idx = vox * 128 + (((g ^ (vox & 7))) << 3) + (sub & 1) * 4;
        *(ushort4*)&smem[32768 + idx] = hh;
        *(ushort4*)&smem[36864 + idx] = ll;
    }
    __syncthreads();

    // ---- phase 2 MFMA: [32 x 128] @ [128 x 128] ----
    const int lm = l & 15, lk = l >> 4;

    s16x8 ah[2][4], al[2][4];
    #pragma unroll
    for (int rt = 0; rt < 2; ++rt) {
        const int rowA = rt * 16 + lm;
        #pragma unroll
        for (int kb = 0; kb < 4; ++kb) {
            const int g = kb * 4 + lk;
            ah[rt][kb] = *(const s16x8*)&smem[32768 + BSW(rowA, g)];
            al[rt][kb] = *(const s16x8*)&smem[36864 + BSW(rowA, g)];
        }
    }

    f32x4 acc2[2][2];
    #pragma unroll
    for (int rt = 0; rt < 2; ++rt)
        #pragma unroll
        for (int ct = 0; ct < 2; ++ct)
            #pragma unroll
            for (int r = 0; r < 4; ++r) acc2[rt][ct][r] = 0.f;

    const int ncol = wv * 32;
    #pragma unroll
    for (int ct = 0; ct < 2; ++ct) {
        const int n  = ncol + ct * 16 + lm;
        const int hb = (n >= 64) ? 16384 : 0;
        const int nn = n & 63;
        s16x8 bh[4], bl[4];
        #pragma unroll
        for (int kb = 0; kb < 4; ++kb) {
            const int g = kb * 4 + lk;
            bh[kb] = *(const s16x8*)&smem[hb + BSW(nn, g)];
            bl[kb] = *(const s16x8*)&smem[hb + 8192 + BSW(nn, g)];
        }
        #pragma unroll
        for (int rt = 0; rt < 2; ++rt)
            #pragma unroll
            for (int kb = 0; kb < 4; ++kb) {
                acc2[rt][ct] = __builtin_amdgcn_mfma_f32_16x16x32_bf16(ah[rt][kb], bh[kb], acc2[rt][ct], 0, 0, 0);
                acc2[rt][ct] = __builtin_amdgcn_mfma_f32_16x16x32_bf16(ah[rt][kb], bl[kb], acc2[rt][ct], 0, 0, 0);
                acc2[rt][ct] = __builtin_amdgcn_mfma_f32_16x16x32_bf16(al[rt][kb], bh[kb], acc2[rt][ct], 0, 0, 0);
            }
    }

    #pragma unroll
    for (int rt = 0; rt < 2; ++rt)
        #pragma unroll
        for (int ct = 0; ct < 2; ++ct) {
            const int col = ncol + ct * 16 + lm;
            const float bb = bp[col];
            #pragma unroll
            for (int r = 0; r < 4; ++r) {
                const int vox = rt * 16 + lk * 4 + r;
                const int ld = vox >> 4, lh = (vox >> 2) & 3, lw = vox & 3;
                const int n  = ((d0 + ld) * DD3 + (h0 + lh)) * DD3 + (w0 + lw);
                out[n * 128 + col] = acc2[rt][ct][r] + bb;
            }
        }
}

extern "C" void kernel_launch(void* const* d_in, const int* in_sizes, int n_in,
                              void* d_out, int out_size, void* d_ws, size_t ws_size,
                              hipStream_t stream) {
    const float* x   = (const float*)d_in[0];
    const float* Wq  = (const float*)d_in[1];
    const float* bq  = (const float*)d_in[2];
    const float* Wkv = (const float*)d_in[3];
    const float* bkv = (const float*)d_in[4];
    const float* Wp  = (const float*)d_in[5];
    const float* bp  = (const float*)d_in[6];
    float* out = (float*)d_out;

    // workspace: qb f32 N*128 @0 ; kvb bf16 N*256 @7,077,888 ; wimg @14,155,776
    char* ws = (char*)d_ws;
    float*  qb   = (float*)(ws);
    ushort* kvb  = (ushort*)(ws + 7077888);
    ushort* wimg = (ushort*)(ws + 14155776);

    prep_w<<<64, 256, 0, stream>>>(Wq, Wkv, Wp, wimg);
    dim3 g1(NTOK / 64, 6);
    qkv_fused<<<g1, 256, 0, stream>>>(x, wimg, bq, bkv, qb, kvb);
    attn_proj<<<432, 256, 0, stream>>>((const float4*)qb, (const ushort4*)kvb,
                                       wimg, bp, out);
}